// Round 8
// baseline (825.794 us; speedup 1.0000x reference)
//
#include <hip/hip_runtime.h>
#include <hip/hip_bf16.h>

#define DEV __device__ __forceinline__

typedef __attribute__((ext_vector_type(8))) short short8;
typedef __attribute__((ext_vector_type(4))) float floatx4;

DEV short f2bf(float f) {
  unsigned u = __float_as_uint(f);
  u += 0x7fffu + ((u >> 16) & 1u);
  return (short)(u >> 16);
}
DEV float bf2f(short s) {
  return __uint_as_float(((unsigned)(unsigned short)s) << 16);
}
DEV float wred(float v) {
#pragma unroll
  for (int m = 1; m < 64; m <<= 1) v += __shfl_xor(v, m);
  return v;
}
DEV floatx4 mfma16(short8 a, short8 b, floatx4 c) {
  return __builtin_amdgcn_mfma_f32_16x16x32_bf16(a, b, c, 0, 0, 0);
}
// async global->LDS, 16B per lane, dest = wave-uniform base + lane*16
DEV void gload16(void* lds, const void* g) {
  __builtin_amdgcn_global_load_lds(
      (const __attribute__((address_space(1))) unsigned int*)g,
      (__attribute__((address_space(3))) unsigned int*)lds, 16, 0, 0);
}

// ---------------------------------------------------------------------------
// Weight transpose+convert+scale: src fp32 [K,N] -> dst bf16 [N][kp]
// ---------------------------------------------------------------------------
struct MatDesc { const float* src; int K; int N; int kp; int off; float scale; };
struct MatTable { MatDesc m[36]; };

__global__ __launch_bounds__(256) void wtrans_kernel(MatTable T, short* __restrict__ dst) {
  int mi = blockIdx.y;
  MatDesc d = T.m[mi];
  int tilesx = d.N >> 5, tilesy = d.kp >> 5;
  int tb = blockIdx.x;
  if (tb >= tilesx * tilesy) return;
  int ty = tb / tilesx, tx = tb % tilesx;
  __shared__ float tile[32][33];
  int tid = threadIdx.x;
#pragma unroll
  for (int i = 0; i < 4; ++i) {
    int e = tid + i * 256, lr = e >> 5, lc = e & 31;
    int kk = ty * 32 + lr;
    tile[lr][lc] = (kk < d.K) ? d.src[(size_t)kk * d.N + tx * 32 + lc] : 0.f;
  }
  __syncthreads();
#pragma unroll
  for (int i = 0; i < 4; ++i) {
    int e = tid + i * 256, lr = e >> 5, lc = e & 31;
    dst[(size_t)d.off + (size_t)(tx * 32 + lr) * d.kp + ty * 32 + lc] =
        f2bf(tile[lc][lr] * d.scale);
  }
}

// ---------------------------------------------------------------------------
// NeRF encode -> enc bf16 [32768, 64] (k 48..63 = 0)
// ---------------------------------------------------------------------------
__global__ __launch_bounds__(256) void enc_kernel(const float* __restrict__ pos,
                                                  short* __restrict__ enc) {
  int idx = blockIdx.x * 256 + threadIdx.x;
  int row = idx >> 3, oct = idx & 7;
  float p0 = pos[row * 2], p1 = pos[row * 2 + 1];
  short8 o;
#pragma unroll
  for (int j = 0; j < 8; ++j) {
    int k = oct * 8 + j;
    float val = 0.f;
    if (k < 48) {
      int dd = k / 24, rem = k % 24;
      int trig = rem / 12, f = rem % 12;
      float ang = (dd ? p1 : p0) * exp2f((4.0f / 11.0f) * (float)f);
      val = trig ? __cosf(ang) : __sinf(ang);
    }
    o[j] = f2bf(val);
  }
  *(short8*)&enc[(size_t)row * 64 + oct * 8] = o;
}

// ---------------------------------------------------------------------------
// Fused pos-embed GEMM (enc @ W_pos^T, K=64) + relu + x@W_in + LN(k), LN(v)
// 512 threads = 8 waves; block = 128 rows; params staged in LDS.
// Output: knvn [32768][1024], LN(k) cols 0..511, LN(v) cols 512..1023.
// ---------------------------------------------------------------------------
__global__ __launch_bounds__(512) void embed2_kernel(
    const short* __restrict__ enc, const short* __restrict__ Wt,  // [512][64]
    const float* __restrict__ b_pos, const float* __restrict__ W_in,
    const float* __restrict__ b_in, const float* __restrict__ x,
    const float* __restrict__ lnk_g, const float* __restrict__ lnk_b,
    const float* __restrict__ lnv_g, const float* __restrict__ lnv_b,
    short* __restrict__ knvn) {
  __shared__ short Wl[512 * 64];   // 64 KB
  __shared__ short El[128 * 64];   // 16 KB
  __shared__ float Pf[9 * 512];    // 18 KB params
  int tid = threadIdx.x;
  int lane = tid & 63, wv = tid >> 6;
  int c = lane & 15, g = lane >> 4;
  int blk = blockIdx.x * 128;
#pragma unroll
  for (int gi = 0; gi < 8; ++gi) {
    int grp = wv * 8 + gi;
    int row = grp * 8 + (lane >> 3), kc = lane & 7;
    gload16(&Wl[grp * 512], &Wt[(size_t)row * 64 + ((kc ^ (row & 7)) * 8)]);
  }
#pragma unroll
  for (int gi = 0; gi < 2; ++gi) {
    int grp = wv * 2 + gi;
    int row = grp * 8 + (lane >> 3), kc = lane & 7;
    gload16(&El[grp * 512], &enc[(size_t)(blk + row) * 64 + ((kc ^ (row & 7)) * 8)]);
  }
  Pf[tid]        = b_pos[tid];
  Pf[512 + tid]  = W_in[tid];
  Pf[1024 + tid] = W_in[512 + tid];
  Pf[1536 + tid] = W_in[1024 + tid];
  Pf[2048 + tid] = b_in[tid];
  Pf[2560 + tid] = lnk_g[tid];
  Pf[3072 + tid] = lnk_b[tid];
  Pf[3584 + tid] = lnv_g[tid];
  Pf[4096 + tid] = lnv_b[tid];
  __syncthreads();

  floatx4 acc[32];
  floatx4 zf = {0.f, 0.f, 0.f, 0.f};
#pragma unroll
  for (int nf = 0; nf < 32; ++nf) acc[nf] = zf;
  short8 af[2];
#pragma unroll
  for (int ks = 0; ks < 2; ++ks)
    af[ks] = *(const short8*)&El[(wv * 16 + c) * 64 + ((ks * 4 + g) ^ (c & 7)) * 8];
#pragma unroll
  for (int nf = 0; nf < 32; ++nf) {
#pragma unroll
    for (int ks = 0; ks < 2; ++ks) {
      short8 bf8 = *(const short8*)&Wl[(nf * 16 + c) * 64 + ((ks * 4 + g) ^ (c & 7)) * 8];
      acc[nf] = mfma16(af[ks], bf8, acc[nf]);
    }
  }

  int rowbase = blk + wv * 16 + g * 4;
  float x0[4], x1[4], x2[4];
  float s1[4], q1[4], s2[4], q2[4];
#pragma unroll
  for (int r = 0; r < 4; ++r) {
    x0[r] = x[(size_t)(rowbase + r) * 3];
    x1[r] = x[(size_t)(rowbase + r) * 3 + 1];
    x2[r] = x[(size_t)(rowbase + r) * 3 + 2];
    s1[r] = 0; q1[r] = 0; s2[r] = 0; q2[r] = 0;
  }
#pragma unroll
  for (int nf = 0; nf < 32; ++nf) {
    int col = nf * 16 + c;
    float bp = Pf[col];
    float w0 = Pf[512 + col], w1 = Pf[1024 + col], w2 = Pf[1536 + col], bi = Pf[2048 + col];
#pragma unroll
    for (int r = 0; r < 4; ++r) {
      float kk = fmaxf(acc[nf][r] + bp, 0.f);
      float vv = kk + x0[r] * w0 + x1[r] * w1 + x2[r] * w2 + bi;
      acc[nf][r] = kk;
      s1[r] += kk; q1[r] += kk * kk; s2[r] += vv; q2[r] += vv * vv;
    }
  }
  float m1[4], r1[4], m2[4], r2[4];
#pragma unroll
  for (int r = 0; r < 4; ++r) {
#pragma unroll
    for (int msk = 1; msk < 16; msk <<= 1) {
      s1[r] += __shfl_xor(s1[r], msk); q1[r] += __shfl_xor(q1[r], msk);
      s2[r] += __shfl_xor(s2[r], msk); q2[r] += __shfl_xor(q2[r], msk);
    }
    m1[r] = s1[r] * (1.f / 512.f);
    r1[r] = rsqrtf(q1[r] * (1.f / 512.f) - m1[r] * m1[r] + 1e-5f);
    m2[r] = s2[r] * (1.f / 512.f);
    r2[r] = rsqrtf(q2[r] * (1.f / 512.f) - m2[r] * m2[r] + 1e-5f);
  }
#pragma unroll
  for (int nf = 0; nf < 32; ++nf) {
    int col = nf * 16 + c;
    float w0 = Pf[512 + col], w1 = Pf[1024 + col], w2 = Pf[1536 + col], bi = Pf[2048 + col];
    float gk = Pf[2560 + col], bk = Pf[3072 + col];
    float gv = Pf[3584 + col], bv = Pf[4096 + col];
#pragma unroll
    for (int r = 0; r < 4; ++r) {
      float kk = acc[nf][r];
      float vv = kk + x0[r] * w0 + x1[r] * w1 + x2[r] * w2 + bi;
      size_t ridx = (size_t)(rowbase + r) * 1024;
      knvn[ridx + col] = f2bf((kk - m1[r]) * r1[r] * gk + bk);
      knvn[ridx + 512 + col] = f2bf((vv - m2[r]) * r2[r] * gv + bv);
    }
  }
}

// ---------------------------------------------------------------------------
// LayerNorm fp32 in [M,512] -> bf16 out, one wave per row
// ---------------------------------------------------------------------------
__global__ __launch_bounds__(256) void ln_kernel(
    const float* __restrict__ in, const float* __restrict__ g,
    const float* __restrict__ b, short* __restrict__ out, int M) {
  int row = blockIdx.x * 4 + (threadIdx.x >> 6);
  if (row >= M) return;
  int lane = threadIdx.x & 63;
  float v[8]; float s = 0, q = 0;
#pragma unroll
  for (int j = 0; j < 8; ++j) {
    v[j] = in[(size_t)row * 512 + lane + 64 * j];
    s += v[j]; q += v[j] * v[j];
  }
  s = wred(s); q = wred(q);
  float m = s * (1.f / 512.f);
  float rs = rsqrtf(q * (1.f / 512.f) - m * m + 1e-5f);
#pragma unroll
  for (int j = 0; j < 8; ++j) {
    int cc = lane + 64 * j;
    out[(size_t)row * 512 + cc] = f2bf((v[j] - m) * rs * g[cc] + b[cc]);
  }
}

// broadcast latents [256,512] -> lat [2048,512] fp32
__global__ void bcast_kernel(const float* __restrict__ latents, float* __restrict__ lat) {
  int i = blockIdx.x * 256 + threadIdx.x;
  lat[i] = latents[i & 131071];
}

// ---------------------------------------------------------------------------
// Shared GEMM epilogue op
// EPI: 0 = bf16 out, 1 = gelu->bf16, 2 = fp32 residual +=, 3 = fp32 out
// ---------------------------------------------------------------------------
template <int EPI>
DEV void epi_store(void* outp, size_t idx, float xv) {
  if (EPI == 0) {
    ((short*)outp)[idx] = f2bf(xv);
  } else if (EPI == 1) {
    float t = 0.7978845608f * (xv + 0.044715f * xv * xv * xv);
    ((short*)outp)[idx] = f2bf(0.5f * xv * (1.f + tanhf(t)));
  } else if (EPI == 2) {
    ((float*)outp)[idx] += xv;
  } else {
    ((float*)outp)[idx] = xv;
  }
}

// ---------------------------------------------------------------------------
// GEMM 128x128 tile, BK=64, 4 waves (2x2). A bf16 [M,*lda]; Wt bf16 [N][K].
// XCD-aware block swizzle (requires gridDim.x*gridDim.y % 8 == 0).
// ---------------------------------------------------------------------------
template <int EPI>
__global__ __launch_bounds__(256) void gemm_kernel(
    const short* __restrict__ A, const short* __restrict__ Wt,
    const float* __restrict__ bias, void* __restrict__ outp,
    int M, int N, int K, int lda, int ldo) {
  __shared__ short Alds[128 * 64];
  __shared__ short Blds[128 * 64];
  int tid = threadIdx.x;
  // XCD swizzle: contiguous chunk of tiles per XCD
  int nwg = gridDim.x * gridDim.y;
  int id = blockIdx.y * gridDim.x + blockIdx.x;
  int cpx = nwg >> 3;
  id = (id & 7) * cpx + (id >> 3);
  int brow = (id / gridDim.x) * 128, bcol = (id % gridDim.x) * 128;
  int lane = tid & 63, wvid = tid >> 6;
  int wr = wvid >> 1, wc = wvid & 1;
  int g = lane >> 4, c = lane & 15;
  floatx4 zf = {0.f, 0.f, 0.f, 0.f};
  floatx4 acc[4][4];
#pragma unroll
  for (int i = 0; i < 4; ++i)
#pragma unroll
    for (int j = 0; j < 4; ++j) acc[i][j] = zf;

  int srow = (lane >> 3), skc = lane & 7;
  for (int k0 = 0; k0 < K; k0 += 64) {
#pragma unroll
    for (int gi = 0; gi < 4; ++gi) {
      int grp = wvid * 4 + gi;
      int row = grp * 8 + srow;
      int sw = ((skc ^ (row & 7)) * 8);
      gload16(&Alds[grp * 512], &A[(size_t)(brow + row) * lda + k0 + sw]);
      gload16(&Blds[grp * 512], &Wt[(size_t)(bcol + row) * K + k0 + sw]);
    }
    __syncthreads();
#pragma unroll
    for (int ks = 0; ks < 2; ++ks) {
      int slot = ((ks * 4 + g) ^ (c & 7)) * 8;
      short8 af[4], bf8[4];
#pragma unroll
      for (int mf = 0; mf < 4; ++mf)
        af[mf] = *(const short8*)&Alds[(wr * 64 + mf * 16 + c) * 64 + slot];
#pragma unroll
      for (int nf = 0; nf < 4; ++nf)
        bf8[nf] = *(const short8*)&Blds[(wc * 64 + nf * 16 + c) * 64 + slot];
#pragma unroll
      for (int mf = 0; mf < 4; ++mf)
#pragma unroll
        for (int nf = 0; nf < 4; ++nf)
          acc[mf][nf] = mfma16(af[mf], bf8[nf], acc[mf][nf]);
    }
    __syncthreads();
  }

#pragma unroll
  for (int mf = 0; mf < 4; ++mf) {
#pragma unroll
    for (int nf = 0; nf < 4; ++nf) {
      int col = bcol + wc * 64 + nf * 16 + c;
      float bv = bias ? bias[col] : 0.f;
      int row0 = brow + wr * 64 + mf * 16 + g * 4;
#pragma unroll
      for (int r = 0; r < 4; ++r)
        epi_store<EPI>(outp, (size_t)(row0 + r) * ldo + col, acc[mf][nf][r] + bv);
    }
  }
}

// ---------------------------------------------------------------------------
// GEMM 64x64 tile. 4 waves (2x2), each wave 32x32.
// ---------------------------------------------------------------------------
template <int EPI>
__global__ __launch_bounds__(256) void gemm64_kernel(
    const short* __restrict__ A, const short* __restrict__ Wt,
    const float* __restrict__ bias, void* __restrict__ outp,
    int M, int N, int K, int lda, int ldo) {
  __shared__ short Alds[64 * 64];
  __shared__ short Blds[64 * 64];
  int tid = threadIdx.x;
  int brow = blockIdx.y * 64, bcol = blockIdx.x * 64;
  int lane = tid & 63, wvid = tid >> 6;
  int wr = wvid >> 1, wc = wvid & 1;
  int g = lane >> 4, c = lane & 15;
  floatx4 zf = {0.f, 0.f, 0.f, 0.f};
  floatx4 acc[2][2];
#pragma unroll
  for (int i = 0; i < 2; ++i)
#pragma unroll
    for (int j = 0; j < 2; ++j) acc[i][j] = zf;

  int srow = (lane >> 3), skc = lane & 7;
  for (int k0 = 0; k0 < K; k0 += 64) {
#pragma unroll
    for (int gi = 0; gi < 2; ++gi) {
      int grp = wvid * 2 + gi;
      int row = grp * 8 + srow;
      int sw = ((skc ^ (row & 7)) * 8);
      gload16(&Alds[grp * 512], &A[(size_t)(brow + row) * lda + k0 + sw]);
      gload16(&Blds[grp * 512], &Wt[(size_t)(bcol + row) * K + k0 + sw]);
    }
    __syncthreads();
#pragma unroll
    for (int ks = 0; ks < 2; ++ks) {
      int slot = ((ks * 4 + g) ^ (c & 7)) * 8;
      short8 af[2], bf8[2];
#pragma unroll
      for (int mf = 0; mf < 2; ++mf)
        af[mf] = *(const short8*)&Alds[(wr * 32 + mf * 16 + c) * 64 + slot];
#pragma unroll
      for (int nf = 0; nf < 2; ++nf)
        bf8[nf] = *(const short8*)&Blds[(wc * 32 + nf * 16 + c) * 64 + slot];
#pragma unroll
      for (int mf = 0; mf < 2; ++mf)
#pragma unroll
        for (int nf = 0; nf < 2; ++nf)
          acc[mf][nf] = mfma16(af[mf], bf8[nf], acc[mf][nf]);
    }
    __syncthreads();
  }

#pragma unroll
  for (int mf = 0; mf < 2; ++mf) {
#pragma unroll
    for (int nf = 0; nf < 2; ++nf) {
      int col = bcol + wc * 32 + nf * 16 + c;
      float bv = bias ? bias[col] : 0.f;
      int row0 = brow + wr * 32 + mf * 16 + g * 4;
#pragma unroll
      for (int r = 0; r < 4; ++r)
        epi_store<EPI>(outp, (size_t)(row0 + r) * ldo + col, acc[mf][nf][r] + bv);
    }
  }
}

// ---------------------------------------------------------------------------
// Split-KV flash attention, 64-row Q tile, 4 waves (wave = 16 q rows).
// Q pre-scaled by DH^-0.5 (folded into Wq). qbrows==0 => q shared across b.
// XCD-locality decode: the 4 qt-tiles sharing one (h,bz) KV slice map to the
// SAME XCD (lin = x + 8t, qt = t&3, (h,bz) = (t>>2)*8 + x).
// DIRECT=false: write unnormalized partial O fp32 + m,l (split-KV).
// DIRECT=true : lognseg==0; write normalized bf16 straight to outd.
// ---------------------------------------------------------------------------
template <bool DIRECT>
__global__ __launch_bounds__(256) void flashsp_kernel(
    const short* __restrict__ q, const short* __restrict__ k,
    const short* __restrict__ v, float* __restrict__ po,
    float* __restrict__ pm, float* __restrict__ pl,
    short* __restrict__ outd,
    int qrs, int qbrows, long kvbstride, int kvrstride,
    int seglen, int lognseg) {
  __shared__ short Qs[64 * 64];
  __shared__ short Ks[64 * 64];
  __shared__ short Vt[64 * 72];
  __shared__ short Ps[64 * 72];
  int tid = threadIdx.x;
  // XCD-locality block decode
  int lin = blockIdx.x + 4 * blockIdx.y + 32 * blockIdx.z;
  int xg = lin & 7, t = lin >> 3;
  int qt = t & 3;
  int m = (t >> 2) * 8 + xg;
  int h = m & 7, bz = m >> 3;
  int b = bz >> lognseg, seg = bz & ((1 << lognseg) - 1);
  int lane = tid & 63, wv = tid >> 6;
  int g = lane >> 4, c = lane & 15;
  int srow = lane >> 3, skc = lane & 7;

#pragma unroll
  for (int gi = 0; gi < 2; ++gi) {
    int grp = wv * 2 + gi;
    int row = grp * 8 + srow;
    int sw = ((skc ^ (row & 7)) * 8);
    gload16(&Qs[grp * 512],
            &q[((size_t)(b * qbrows) + qt * 64 + row) * qrs + h * 64 + sw]);
  }

  float m_[4], l_[4];
  floatx4 zf = {0.f, 0.f, 0.f, 0.f};
  floatx4 o_[4];
#pragma unroll
  for (int r = 0; r < 4; ++r) { m_[r] = -3.0e38f; l_[r] = 0.f; }
#pragma unroll
  for (int f = 0; f < 4; ++f) o_[f] = zf;

  int tbeg = seg * seglen, tend = tbeg + seglen;
  for (int t0 = tbeg; t0 < tend; t0 += 64) {
#pragma unroll
    for (int gi = 0; gi < 2; ++gi) {
      int grp = wv * 2 + gi;
      int row = grp * 8 + srow;
      int sw = ((skc ^ (row & 7)) * 8);
      gload16(&Ks[grp * 512],
              &k[(size_t)b * kvbstride + (size_t)(t0 + row) * kvrstride + h * 64 + sw]);
    }
#pragma unroll
    for (int it = 0; it < 2; ++it) {
      int ch = tid + it * 256;
      int j = ch >> 3, f0 = (ch & 7) * 8, mm = ch & 7, tg = j >> 3;
      short8 tv = *(const short8*)&v[(size_t)b * kvbstride + (size_t)(t0 + j) * kvrstride + h * 64 + f0];
#pragma unroll
      for (int jj = 0; jj < 8; ++jj)
        Vt[(f0 + jj) * 72 + ((tg ^ mm) * 8) + (j & 7)] = tv[jj];
    }
    __syncthreads();

    floatx4 s[4];
#pragma unroll
    for (int f = 0; f < 4; ++f) s[f] = zf;
#pragma unroll
    for (int ks = 0; ks < 2; ++ks) {
      int slot = ((ks * 4 + g) ^ (c & 7)) * 8;
      short8 a = *(const short8*)&Qs[(wv * 16 + c) * 64 + slot];
#pragma unroll
      for (int f = 0; f < 4; ++f) {
        short8 b8 = *(const short8*)&Ks[(f * 16 + c) * 64 + slot];
        s[f] = mfma16(a, b8, s[f]);
      }
    }

    float nm[4], sf[4], rs[4];
#pragma unroll
    for (int r = 0; r < 4; ++r) {
      float tmax = fmaxf(fmaxf(s[0][r], s[1][r]), fmaxf(s[2][r], s[3][r]));
#pragma unroll
      for (int msk = 1; msk < 16; msk <<= 1) tmax = fmaxf(tmax, __shfl_xor(tmax, msk));
      nm[r] = fmaxf(m_[r], tmax);
      sf[r] = __expf(m_[r] - nm[r]);
      rs[r] = 0.f;
    }
#pragma unroll
    for (int f = 0; f < 4; ++f)
#pragma unroll
      for (int r = 0; r < 4; ++r) {
        float p = __expf(s[f][r] - nm[r]);
        s[f][r] = p; rs[r] += p;
      }
#pragma unroll
    for (int r = 0; r < 4; ++r) {
#pragma unroll
      for (int msk = 1; msk < 16; msk <<= 1) rs[r] += __shfl_xor(rs[r], msk);
      l_[r] = l_[r] * sf[r] + rs[r];
      m_[r] = nm[r];
    }
#pragma unroll
    for (int f = 0; f < 4; ++f)
#pragma unroll
      for (int r = 0; r < 4; ++r) o_[f][r] *= sf[r];
#pragma unroll
    for (int f = 0; f < 4; ++f)
#pragma unroll
      for (int r = 0; r < 4; ++r)
        Ps[(wv * 16 + g * 4 + r) * 72 + f * 16 + c] = f2bf(s[f][r]);
    __syncthreads();
#pragma unroll
    for (int ks = 0; ks < 2; ++ks) {
      short8 pa = *(const short8*)&Ps[(wv * 16 + c) * 72 + ks * 32 + g * 8];
#pragma unroll
      for (int f = 0; f < 4; ++f) {
        int mm = (2 * f + (c >> 3)) & 7;
        short8 vb = *(const short8*)&Vt[(f * 16 + c) * 72 + ((ks * 4 + g) ^ mm) * 8];
        o_[f] = mfma16(pa, vb, o_[f]);
      }
    }
    __syncthreads();
  }

#pragma unroll
  for (int f = 0; f < 4; ++f)
#pragma unroll
    for (int r = 0; r < 4; ++r) {
      int row = qt * 64 + wv * 16 + g * 4 + r;
      if (DIRECT) {
        outd[((size_t)(b * 256 + row)) * 512 + h * 64 + f * 16 + c] =
            f2bf(o_[f][r] / l_[r]);
      } else {
        size_t grow = (size_t)seg * 2048 + b * 256 + row;
        po[grow * 512 + h * 64 + f * 16 + c] = o_[f][r];
        if (f == 0 && c == 0) {
          pm[grow * 8 + h] = m_[r];
          pl[grow * 8 + h] = l_[r];
        }
      }
    }
}

// ---------------------------------------------------------------------------
// Combine NSEG partial attention results -> bf16 out [2048,512]
// ---------------------------------------------------------------------------
template <int NSEG>
__global__ __launch_bounds__(256) void fcomb_kernel(
    const float* __restrict__ po, const float* __restrict__ pm,
    const float* __restrict__ pl, short* __restrict__ out) {
  int idx = blockIdx.x * 256 + threadIdx.x;  // over 2048*512
  int grow = idx >> 9, col = idx & 511, h = col >> 6;
  float ms[NSEG];
  float M = -3.0e38f;
#pragma unroll
  for (int s = 0; s < NSEG; ++s) {
    ms[s] = pm[((size_t)s * 2048 + grow) * 8 + h];
    M = fmaxf(M, ms[s]);
  }
  float L = 0.f, acc = 0.f;
#pragma unroll
  for (int s = 0; s < NSEG; ++s) {
    float w = __expf(ms[s] - M);
    L += w * pl[((size_t)s * 2048 + grow) * 8 + h];
    acc += w * po[((size_t)s * 2048 + grow) * 512 + col];
  }
  out[idx] = f2bf(acc / L);
}

// ---------------------------------------------------------------------------
extern "C" void kernel_launch(void* const* d_in, const int* in_sizes, int n_in,
                              void* d_out, int out_size, void* d_ws, size_t ws_size,
                              hipStream_t stream) {
  const float* x       = (const float*)d_in[0];
  const float* pos     = (const float*)d_in[1];
  const float* W_pos   = (const float*)d_in[2];
  const float* b_pos   = (const float*)d_in[3];
  const float* W_in    = (const float*)d_in[4];
  const float* b_in    = (const float*)d_in[5];
  const float* latents = (const float*)d_in[6];
  const float* lnq_g   = (const float*)d_in[7];
  const float* lnq_b   = (const float*)d_in[8];
  const float* lnk_g   = (const float*)d_in[9];
  const float* lnk_b   = (const float*)d_in[10];
  const float* lnv_g   = (const float*)d_in[11];
  const float* lnv_b   = (const float*)d_in[12];
  const float* cWq     = (const float*)d_in[13];
  const float* cWk     = (const float*)d_in[14];
  const float* cWv     = (const float*)d_in[15];
  const float* cWo     = (const float*)d_in[16];
  const float* c_bo    = (const float*)d_in[17];
  const float* ln1_g   = (const float*)d_in[18];
  const float* ln1_b   = (const float*)d_in[19];
  const float* sWq     = (const float*)d_in[20];
  const float* sWkv    = (const float*)d_in[21];
  const float* sWo     = (const float*)d_in[22];
  const float* s_bo    = (const float*)d_in[23];
  const float* ln2_g   = (const float*)d_in[24];
  const float* ln2_b   = (const float*)d_in[25];
  const float* fW1     = (const float*)d_in[26];
  const float* f_b1    = (const float*)d_in[27];
  const float* fW2     = (const float*)d_in[28];
  const float* f_b2    = (const float*)d_in[29];
  const float* lnf_g   = (const float*)d_in[30];
  const float* lnf_b   = (const float*)d_in[31];
  const float* Wb      = (const float*)d_in[32];
  const float* bbv     = (const float*)d_in[33];
  float* outp = (float*)d_out;

  // bf16 transposed weight offsets (elements)
  size_t W = 0;
  size_t o_cWq = W; W += 512 * 512;
  size_t o_cWk = W; W += 512 * 512;
  size_t o_cWv = W; W += 512 * 512;
  size_t o_cWo = W; W += 512 * 512;
  size_t o_Wb  = W; W += 64 * 512;
  size_t o_Wpos = W; W += 512 * 64;
  size_t o_sQKV[6], o_sWo[6], o_fW1[6], o_fW2[6];
  for (int i = 0; i < 6; ++i) {
    o_sQKV[i] = W; W += 1536 * 512;   // q rows 0..511 (pre-scaled), kv rows 512..1535
    o_sWo[i]  = W; W += 512 * 512;
    o_fW1[i]  = W; W += 2048 * 512;
    o_fW2[i]  = W; W += 512 * 2048;
  }
  MatTable T;
  int nm = 0;
  auto add = [&](const float* s, int K, int N, int kp, size_t off, float sc) {
    T.m[nm].src = s; T.m[nm].K = K; T.m[nm].N = N; T.m[nm].kp = kp;
    T.m[nm].off = (int)off; T.m[nm].scale = sc; ++nm;
  };
  const float SC = 0.125f;  // DH^-0.5 folded into Wq
  add(cWq, 512, 512, 512, o_cWq, SC); add(cWk, 512, 512, 512, o_cWk, 1.f);
  add(cWv, 512, 512, 512, o_cWv, 1.f); add(cWo, 512, 512, 512, o_cWo, 1.f);
  add(Wb, 512, 64, 512, o_Wb, 1.f);
  add(W_pos, 48, 512, 64, o_Wpos, 1.f);
  for (int i = 0; i < 6; ++i) {
    add(sWq  + (size_t)i * 512 * 512,  512, 512,  512, o_sQKV[i], SC);
    add(sWkv + (size_t)i * 512 * 1024, 512, 1024, 512, o_sQKV[i] + 512 * 512, 1.f);
    add(sWo  + (size_t)i * 512 * 512,  512, 512,  512, o_sWo[i], 1.f);
    add(fW1  + (size_t)i * 512 * 2048, 512, 2048, 512, o_fW1[i], 1.f);
    add(fW2  + (size_t)i * 2048 * 512, 2048, 512, 2048, o_fW2[i], 1.f);
  }

  // workspace carve
  char* p = (char*)d_ws;
  auto carve = [&](size_t bytes) {
    char* r = p; p += (bytes + 255) & ~(size_t)255; return r;
  };
  short* wtb   = (short*)carve(W * 2);                     // ~40MB
  short* enc   = (short*)carve((size_t)32768 * 64 * 2);    // 4MB
  short* knvn  = (short*)carve((size_t)32768 * 1024 * 2);  // 64MB  [k | v]
  short* kvc   = (short*)carve((size_t)32768 * 1024 * 2);  // 64MB  [K | V]
  short* latn0 = (short*)carve(262144);
  short* qc    = (short*)carve(262144);
  float* lat   = (float*)carve(4194304);
  float* pm    = (float*)carve(1048576);
  float* pl    = (float*)carve(1048576);
  // aliases into dead regions:
  short* attno = enc;                                  // enc dead after embed2
  float* po    = (float*)knvn;                         // knvn dead after projections
  short* h     = (short*)((char*)knvn + 36 * 1048576);
  short* qkv   = (short*)((char*)knvn + 40 * 1048576);
  short* ffh   = (short*)((char*)knvn + 48 * 1048576);

  wtrans_kernel<<<dim3(1024, 36), 256, 0, stream>>>(T, wtb);
  enc_kernel<<<1024, 256, 0, stream>>>(pos, enc);
  embed2_kernel<<<256, 512, 0, stream>>>(enc, wtb + o_Wpos, b_pos, W_in, b_in, x,
                                         lnk_g, lnk_b, lnv_g, lnv_b, knvn);
  bcast_kernel<<<4096, 256, 0, stream>>>(latents, lat);
  ln_kernel<<<64, 256, 0, stream>>>(latents, lnq_g, lnq_b, latn0, 256);
  gemm64_kernel<0><<<dim3(8, 4), 256, 0, stream>>>(latn0, wtb + o_cWq, nullptr, qc, 256, 512, 512, 512, 512);
  gemm_kernel<0><<<dim3(4, 256), 256, 0, stream>>>(knvn, wtb + o_cWk, nullptr, kvc, 32768, 512, 512, 1024, 1024);
  gemm_kernel<0><<<dim3(4, 256), 256, 0, stream>>>(knvn + 512, wtb + o_cWv, nullptr, kvc + 512, 32768, 512, 512, 1024, 1024);
  // cross attention: 8 KV segments of 512 tokens; qc shared across b (qbrows=0)
  flashsp_kernel<false><<<dim3(4, 8, 64), 256, 0, stream>>>(qc, kvc, kvc + 512, po, pm, pl,
                                                            nullptr, 512, 0,
                                                            (long)4096 * 1024, 1024, 512, 3);
  fcomb_kernel<8><<<4096, 256, 0, stream>>>(po, pm, pl, attno);
  gemm64_kernel<2><<<dim3(8, 32), 256, 0, stream>>>(attno, wtb + o_cWo, c_bo, lat, 2048, 512, 512, 512, 512);

  for (int i = 0; i < 6; ++i) {
    ln_kernel<<<512, 256, 0, stream>>>(lat, ln1_g + i * 512, ln1_b + i * 512, h, 2048);
    gemm_kernel<0><<<dim3(12, 16), 256, 0, stream>>>(h, wtb + o_sQKV[i], nullptr, qkv, 2048, 1536, 512, 512, 1536);
    // self attention: no split, direct normalized bf16 output (per-batch q)
    flashsp_kernel<true><<<dim3(4, 8, 8), 256, 0, stream>>>(qkv, qkv + 512, qkv + 1024,
                                                            nullptr, nullptr, nullptr, attno,
                                                            1536, 256, (long)256 * 1536, 1536, 256, 0);
    gemm64_kernel<2><<<dim3(8, 32), 256, 0, stream>>>(attno, wtb + o_sWo[i], s_bo + i * 512, lat, 2048, 512, 512, 512, 512);
    ln_kernel<<<512, 256, 0, stream>>>(lat, ln2_g + i * 512, ln2_b + i * 512, h, 2048);
    gemm_kernel<1><<<dim3(16, 16), 256, 0, stream>>>(h, wtb + o_fW1[i], f_b1 + i * 2048, ffh, 2048, 2048, 512, 512, 2048);
    gemm64_kernel<2><<<dim3(8, 32), 256, 0, stream>>>(ffh, wtb + o_fW2[i], f_b2 + i * 512, lat, 2048, 512, 2048, 2048, 512);
  }
  ln_kernel<<<512, 256, 0, stream>>>(lat, lnf_g, lnf_b, h, 2048);
  gemm64_kernel<3><<<dim3(1, 32), 256, 0, stream>>>(h, wtb + o_Wb, bbv, outp, 2048, 64, 512, 512, 64);
}

// Round 9
// 824.236 us; speedup vs baseline: 1.0019x; 1.0019x over previous
//
#include <hip/hip_runtime.h>
#include <hip/hip_bf16.h>

#define DEV __device__ __forceinline__

typedef __attribute__((ext_vector_type(8))) short short8;
typedef __attribute__((ext_vector_type(4))) float floatx4;

DEV short f2bf(float f) {
  unsigned u = __float_as_uint(f);
  u += 0x7fffu + ((u >> 16) & 1u);
  return (short)(u >> 16);
}
DEV float bf2f(short s) {
  return __uint_as_float(((unsigned)(unsigned short)s) << 16);
}
DEV float wred(float v) {
#pragma unroll
  for (int m = 1; m < 64; m <<= 1) v += __shfl_xor(v, m);
  return v;
}
DEV floatx4 mfma16(short8 a, short8 b, floatx4 c) {
  return __builtin_amdgcn_mfma_f32_16x16x32_bf16(a, b, c, 0, 0, 0);
}
// async global->LDS, 16B per lane, dest = wave-uniform base + lane*16
DEV void gload16(void* lds, const void* g) {
  __builtin_amdgcn_global_load_lds(
      (const __attribute__((address_space(1))) unsigned int*)g,
      (__attribute__((address_space(3))) unsigned int*)lds, 16, 0, 0);
}

// ---------------------------------------------------------------------------
// Weight transpose+convert+scale: src fp32 [K,N] -> dst bf16 [N][kp]
// ---------------------------------------------------------------------------
struct MatDesc { const float* src; int K; int N; int kp; int off; float scale; };
struct MatTable { MatDesc m[36]; };

__global__ __launch_bounds__(256) void wtrans_kernel(MatTable T, short* __restrict__ dst) {
  int mi = blockIdx.y;
  MatDesc d = T.m[mi];
  int tilesx = d.N >> 5, tilesy = d.kp >> 5;
  int tb = blockIdx.x;
  if (tb >= tilesx * tilesy) return;
  int ty = tb / tilesx, tx = tb % tilesx;
  __shared__ float tile[32][33];
  int tid = threadIdx.x;
#pragma unroll
  for (int i = 0; i < 4; ++i) {
    int e = tid + i * 256, lr = e >> 5, lc = e & 31;
    int kk = ty * 32 + lr;
    tile[lr][lc] = (kk < d.K) ? d.src[(size_t)kk * d.N + tx * 32 + lc] : 0.f;
  }
  __syncthreads();
#pragma unroll
  for (int i = 0; i < 4; ++i) {
    int e = tid + i * 256, lr = e >> 5, lc = e & 31;
    dst[(size_t)d.off + (size_t)(tx * 32 + lr) * d.kp + ty * 32 + lc] =
        f2bf(tile[lc][lr] * d.scale);
  }
}

// ---------------------------------------------------------------------------
// NeRF encode -> enc bf16 [32768, 64] (k 48..63 = 0)
// ---------------------------------------------------------------------------
__global__ __launch_bounds__(256) void enc_kernel(const float* __restrict__ pos,
                                                  short* __restrict__ enc) {
  int idx = blockIdx.x * 256 + threadIdx.x;
  int row = idx >> 3, oct = idx & 7;
  float p0 = pos[row * 2], p1 = pos[row * 2 + 1];
  short8 o;
#pragma unroll
  for (int j = 0; j < 8; ++j) {
    int k = oct * 8 + j;
    float val = 0.f;
    if (k < 48) {
      int dd = k / 24, rem = k % 24;
      int trig = rem / 12, f = rem % 12;
      float ang = (dd ? p1 : p0) * exp2f((4.0f / 11.0f) * (float)f);
      val = trig ? __cosf(ang) : __sinf(ang);
    }
    o[j] = f2bf(val);
  }
  *(short8*)&enc[(size_t)row * 64 + oct * 8] = o;
}

// ---------------------------------------------------------------------------
// Fused pos-embed GEMM (enc @ W_pos^T, K=64) + relu + x@W_in + LN(k), LN(v)
// 512 threads = 8 waves; block = 128 rows; params staged in LDS.
// Output: knvn [32768][1024], LN(k) cols 0..511, LN(v) cols 512..1023.
// ---------------------------------------------------------------------------
__global__ __launch_bounds__(512) void embed2_kernel(
    const short* __restrict__ enc, const short* __restrict__ Wt,  // [512][64]
    const float* __restrict__ b_pos, const float* __restrict__ W_in,
    const float* __restrict__ b_in, const float* __restrict__ x,
    const float* __restrict__ lnk_g, const float* __restrict__ lnk_b,
    const float* __restrict__ lnv_g, const float* __restrict__ lnv_b,
    short* __restrict__ knvn) {
  __shared__ short Wl[512 * 64];   // 64 KB
  __shared__ short El[128 * 64];   // 16 KB
  __shared__ float Pf[9 * 512];    // 18 KB params
  int tid = threadIdx.x;
  int lane = tid & 63, wv = tid >> 6;
  int c = lane & 15, g = lane >> 4;
  int blk = blockIdx.x * 128;
#pragma unroll
  for (int gi = 0; gi < 8; ++gi) {
    int grp = wv * 8 + gi;
    int row = grp * 8 + (lane >> 3), kc = lane & 7;
    gload16(&Wl[grp * 512], &Wt[(size_t)row * 64 + ((kc ^ (row & 7)) * 8)]);
  }
#pragma unroll
  for (int gi = 0; gi < 2; ++gi) {
    int grp = wv * 2 + gi;
    int row = grp * 8 + (lane >> 3), kc = lane & 7;
    gload16(&El[grp * 512], &enc[(size_t)(blk + row) * 64 + ((kc ^ (row & 7)) * 8)]);
  }
  Pf[tid]        = b_pos[tid];
  Pf[512 + tid]  = W_in[tid];
  Pf[1024 + tid] = W_in[512 + tid];
  Pf[1536 + tid] = W_in[1024 + tid];
  Pf[2048 + tid] = b_in[tid];
  Pf[2560 + tid] = lnk_g[tid];
  Pf[3072 + tid] = lnk_b[tid];
  Pf[3584 + tid] = lnv_g[tid];
  Pf[4096 + tid] = lnv_b[tid];
  __syncthreads();

  floatx4 acc[32];
  floatx4 zf = {0.f, 0.f, 0.f, 0.f};
#pragma unroll
  for (int nf = 0; nf < 32; ++nf) acc[nf] = zf;
  short8 af[2];
#pragma unroll
  for (int ks = 0; ks < 2; ++ks)
    af[ks] = *(const short8*)&El[(wv * 16 + c) * 64 + ((ks * 4 + g) ^ (c & 7)) * 8];
#pragma unroll
  for (int nf = 0; nf < 32; ++nf) {
#pragma unroll
    for (int ks = 0; ks < 2; ++ks) {
      short8 bf8 = *(const short8*)&Wl[(nf * 16 + c) * 64 + ((ks * 4 + g) ^ (c & 7)) * 8];
      acc[nf] = mfma16(af[ks], bf8, acc[nf]);
    }
  }

  int rowbase = blk + wv * 16 + g * 4;
  float x0[4], x1[4], x2[4];
  float s1[4], q1[4], s2[4], q2[4];
#pragma unroll
  for (int r = 0; r < 4; ++r) {
    x0[r] = x[(size_t)(rowbase + r) * 3];
    x1[r] = x[(size_t)(rowbase + r) * 3 + 1];
    x2[r] = x[(size_t)(rowbase + r) * 3 + 2];
    s1[r] = 0; q1[r] = 0; s2[r] = 0; q2[r] = 0;
  }
#pragma unroll
  for (int nf = 0; nf < 32; ++nf) {
    int col = nf * 16 + c;
    float bp = Pf[col];
    float w0 = Pf[512 + col], w1 = Pf[1024 + col], w2 = Pf[1536 + col], bi = Pf[2048 + col];
#pragma unroll
    for (int r = 0; r < 4; ++r) {
      float kk = fmaxf(acc[nf][r] + bp, 0.f);
      float vv = kk + x0[r] * w0 + x1[r] * w1 + x2[r] * w2 + bi;
      acc[nf][r] = kk;
      s1[r] += kk; q1[r] += kk * kk; s2[r] += vv; q2[r] += vv * vv;
    }
  }
  float m1[4], r1[4], m2[4], r2[4];
#pragma unroll
  for (int r = 0; r < 4; ++r) {
#pragma unroll
    for (int msk = 1; msk < 16; msk <<= 1) {
      s1[r] += __shfl_xor(s1[r], msk); q1[r] += __shfl_xor(q1[r], msk);
      s2[r] += __shfl_xor(s2[r], msk); q2[r] += __shfl_xor(q2[r], msk);
    }
    m1[r] = s1[r] * (1.f / 512.f);
    r1[r] = rsqrtf(q1[r] * (1.f / 512.f) - m1[r] * m1[r] + 1e-5f);
    m2[r] = s2[r] * (1.f / 512.f);
    r2[r] = rsqrtf(q2[r] * (1.f / 512.f) - m2[r] * m2[r] + 1e-5f);
  }
#pragma unroll
  for (int nf = 0; nf < 32; ++nf) {
    int col = nf * 16 + c;
    float w0 = Pf[512 + col], w1 = Pf[1024 + col], w2 = Pf[1536 + col], bi = Pf[2048 + col];
    float gk = Pf[2560 + col], bk = Pf[3072 + col];
    float gv = Pf[3584 + col], bv = Pf[4096 + col];
#pragma unroll
    for (int r = 0; r < 4; ++r) {
      float kk = acc[nf][r];
      float vv = kk + x0[r] * w0 + x1[r] * w1 + x2[r] * w2 + bi;
      size_t ridx = (size_t)(rowbase + r) * 1024;
      knvn[ridx + col] = f2bf((kk - m1[r]) * r1[r] * gk + bk);
      knvn[ridx + 512 + col] = f2bf((vv - m2[r]) * r2[r] * gv + bv);
    }
  }
}

// ---------------------------------------------------------------------------
// LayerNorm fp32 in [M,512] -> bf16 out, one wave per row
// ---------------------------------------------------------------------------
__global__ __launch_bounds__(256) void ln_kernel(
    const float* __restrict__ in, const float* __restrict__ g,
    const float* __restrict__ b, short* __restrict__ out, int M) {
  int row = blockIdx.x * 4 + (threadIdx.x >> 6);
  if (row >= M) return;
  int lane = threadIdx.x & 63;
  float v[8]; float s = 0, q = 0;
#pragma unroll
  for (int j = 0; j < 8; ++j) {
    v[j] = in[(size_t)row * 512 + lane + 64 * j];
    s += v[j]; q += v[j] * v[j];
  }
  s = wred(s); q = wred(q);
  float m = s * (1.f / 512.f);
  float rs = rsqrtf(q * (1.f / 512.f) - m * m + 1e-5f);
#pragma unroll
  for (int j = 0; j < 8; ++j) {
    int cc = lane + 64 * j;
    out[(size_t)row * 512 + cc] = f2bf((v[j] - m) * rs * g[cc] + b[cc]);
  }
}

// ---------------------------------------------------------------------------
// Shared GEMM epilogue op
// EPI: 0 = bf16 out, 1 = gelu->bf16, 2 = fp32 residual +=, 3 = fp32 out
//      4 = fp32 out = latents_bcast + acc (+bias)
// ---------------------------------------------------------------------------
template <int EPI>
DEV void epi_store(void* outp, size_t idx, float xv) {
  if (EPI == 0) {
    ((short*)outp)[idx] = f2bf(xv);
  } else if (EPI == 1) {
    float t = 0.7978845608f * (xv + 0.044715f * xv * xv * xv);
    ((short*)outp)[idx] = f2bf(0.5f * xv * (1.f + tanhf(t)));
  } else if (EPI == 2) {
    ((float*)outp)[idx] += xv;
  } else if (EPI == 3) {
    ((float*)outp)[idx] = xv;
  }
}

// ---------------------------------------------------------------------------
// GEMM 128x128 tile, BK=64, 4 waves (2x2). A bf16 [M,*lda]; Wt bf16 [N][K].
// XCD-aware block swizzle (requires gridDim.x*gridDim.y % 8 == 0).
// Optional transposed-V epilogue: blocks with bcol >= vcol0 write C^T into
// vT[b][h][d][tok] (tokpb tokens per (b,h)); used to feed flash attention
// without per-tile LDS transpose scatter.
// ---------------------------------------------------------------------------
template <int EPI>
__global__ __launch_bounds__(256) void gemm_kernel(
    const short* __restrict__ A, const short* __restrict__ Wt,
    const float* __restrict__ bias, void* __restrict__ outp,
    int M, int N, int K, int lda, int ldo,
    short* __restrict__ vT, int vcol0, int tokpb) {
  __shared__ short SL[16384];  // Alds | Blds union; reused for C^T staging
  short* Alds = SL;
  short* Blds = SL + 8192;
  int tid = threadIdx.x;
  // XCD swizzle: contiguous chunk of tiles per XCD
  int nwg = gridDim.x * gridDim.y;
  int id = blockIdx.y * gridDim.x + blockIdx.x;
  int cpx = nwg >> 3;
  id = (id & 7) * cpx + (id >> 3);
  int brow = (id / gridDim.x) * 128, bcol = (id % gridDim.x) * 128;
  int lane = tid & 63, wvid = tid >> 6;
  int wr = wvid >> 1, wc = wvid & 1;
  int g = lane >> 4, c = lane & 15;
  floatx4 zf = {0.f, 0.f, 0.f, 0.f};
  floatx4 acc[4][4];
#pragma unroll
  for (int i = 0; i < 4; ++i)
#pragma unroll
    for (int j = 0; j < 4; ++j) acc[i][j] = zf;

  int srow = (lane >> 3), skc = lane & 7;
  for (int k0 = 0; k0 < K; k0 += 64) {
#pragma unroll
    for (int gi = 0; gi < 4; ++gi) {
      int grp = wvid * 4 + gi;
      int row = grp * 8 + srow;
      int sw = ((skc ^ (row & 7)) * 8);
      gload16(&Alds[grp * 512], &A[(size_t)(brow + row) * lda + k0 + sw]);
      gload16(&Blds[grp * 512], &Wt[(size_t)(bcol + row) * K + k0 + sw]);
    }
    __syncthreads();
#pragma unroll
    for (int ks = 0; ks < 2; ++ks) {
      int slot = ((ks * 4 + g) ^ (c & 7)) * 8;
      short8 af[4], bf8[4];
#pragma unroll
      for (int mf = 0; mf < 4; ++mf)
        af[mf] = *(const short8*)&Alds[(wr * 64 + mf * 16 + c) * 64 + slot];
#pragma unroll
      for (int nf = 0; nf < 4; ++nf)
        bf8[nf] = *(const short8*)&Blds[(wc * 64 + nf * 16 + c) * 64 + slot];
#pragma unroll
      for (int mf = 0; mf < 4; ++mf)
#pragma unroll
        for (int nf = 0; nf < 4; ++nf)
          acc[mf][nf] = mfma16(af[mf], bf8[nf], acc[mf][nf]);
    }
    __syncthreads();
  }

  if (vT != nullptr && bcol >= vcol0) {
    // ---- transposed V epilogue: write C^T to vT[b][h][d][tok] ----
    // stage [128 cols][64 tok-rows] bf16 (stride 66) in two halves
#pragma unroll
    for (int half = 0; half < 2; ++half) {
      __syncthreads();
      if (wr == half) {
#pragma unroll
        for (int mf = 0; mf < 4; ++mf)
#pragma unroll
          for (int nf = 0; nf < 4; ++nf) {
            int lcol = wc * 64 + nf * 16 + c;
            int lrow = mf * 16 + g * 4;
#pragma unroll
            for (int r = 0; r < 4; ++r)
              SL[lcol * 66 + lrow + r] = f2bf(acc[mf][nf][r]);
          }
      }
      __syncthreads();
      int gr = brow + half * 64;
      int bb = gr / tokpb, tok0 = gr % tokpb;
#pragma unroll
      for (int it = 0; it < 2; ++it) {
        int e = it * 256 + tid;
        int colrow = e >> 2, t16 = (e & 3) * 16;
        int hd = bcol + colrow - vcol0;
        short* dst = vT + ((size_t)(bb * 8 + (hd >> 6)) * 64 + (hd & 63)) * tokpb + tok0 + t16;
        *(short8*)dst = *(const short8*)&SL[colrow * 66 + t16];
        *(short8*)(dst + 8) = *(const short8*)&SL[colrow * 66 + t16 + 8];
      }
    }
    return;
  }

#pragma unroll
  for (int mf = 0; mf < 4; ++mf) {
#pragma unroll
    for (int nf = 0; nf < 4; ++nf) {
      int col = bcol + wc * 64 + nf * 16 + c;
      float bv = bias ? bias[col] : 0.f;
      int row0 = brow + wr * 64 + mf * 16 + g * 4;
#pragma unroll
      for (int r = 0; r < 4; ++r)
        epi_store<EPI>(outp, (size_t)(row0 + r) * ldo + col, acc[mf][nf][r] + bv);
    }
  }
}

// ---------------------------------------------------------------------------
// GEMM 64x64 tile. 4 waves (2x2), each wave 32x32.
// EPI==4 uses lat0 (latents broadcast source).
// ---------------------------------------------------------------------------
template <int EPI>
__global__ __launch_bounds__(256) void gemm64_kernel(
    const short* __restrict__ A, const short* __restrict__ Wt,
    const float* __restrict__ bias, void* __restrict__ outp,
    int M, int N, int K, int lda, int ldo, const float* __restrict__ lat0) {
  __shared__ short Alds[64 * 64];
  __shared__ short Blds[64 * 64];
  int tid = threadIdx.x;
  int brow = blockIdx.y * 64, bcol = blockIdx.x * 64;
  int lane = tid & 63, wvid = tid >> 6;
  int wr = wvid >> 1, wc = wvid & 1;
  int g = lane >> 4, c = lane & 15;
  floatx4 zf = {0.f, 0.f, 0.f, 0.f};
  floatx4 acc[2][2];
#pragma unroll
  for (int i = 0; i < 2; ++i)
#pragma unroll
    for (int j = 0; j < 2; ++j) acc[i][j] = zf;

  int srow = (lane >> 3), skc = lane & 7;
  for (int k0 = 0; k0 < K; k0 += 64) {
#pragma unroll
    for (int gi = 0; gi < 2; ++gi) {
      int grp = wvid * 2 + gi;
      int row = grp * 8 + srow;
      int sw = ((skc ^ (row & 7)) * 8);
      gload16(&Alds[grp * 512], &A[(size_t)(brow + row) * lda + k0 + sw]);
      gload16(&Blds[grp * 512], &Wt[(size_t)(bcol + row) * K + k0 + sw]);
    }
    __syncthreads();
#pragma unroll
    for (int ks = 0; ks < 2; ++ks) {
      int slot = ((ks * 4 + g) ^ (c & 7)) * 8;
      short8 af[2], bf8[2];
#pragma unroll
      for (int mf = 0; mf < 2; ++mf)
        af[mf] = *(const short8*)&Alds[(wr * 32 + mf * 16 + c) * 64 + slot];
#pragma unroll
      for (int nf = 0; nf < 2; ++nf)
        bf8[nf] = *(const short8*)&Blds[(wc * 32 + nf * 16 + c) * 64 + slot];
#pragma unroll
      for (int mf = 0; mf < 2; ++mf)
#pragma unroll
        for (int nf = 0; nf < 2; ++nf)
          acc[mf][nf] = mfma16(af[mf], bf8[nf], acc[mf][nf]);
    }
    __syncthreads();
  }

#pragma unroll
  for (int mf = 0; mf < 2; ++mf) {
#pragma unroll
    for (int nf = 0; nf < 2; ++nf) {
      int col = bcol + wc * 32 + nf * 16 + c;
      float bv = bias ? bias[col] : 0.f;
      int row0 = brow + wr * 32 + mf * 16 + g * 4;
#pragma unroll
      for (int r = 0; r < 4; ++r) {
        float xv = acc[mf][nf][r] + bv;
        size_t idx = (size_t)(row0 + r) * ldo + col;
        if (EPI == 4) {
          ((float*)outp)[idx] = lat0[(size_t)((row0 + r) & 255) * 512 + col] + xv;
        } else {
          epi_store<EPI>(outp, idx, xv);
        }
      }
    }
  }
}

// ---------------------------------------------------------------------------
// Split-KV flash attention, 64-row Q tile, 4 waves (wave = 16 q rows).
// Q pre-scaled by DH^-0.5. V supplied TRANSPOSED: vT[b][h][d][tok].
// XCD-locality decode keeps all 4 qt-tiles of one KV slice on one XCD.
// DIRECT=false: write unnormalized partial O fp32 + m,l (split-KV).
// DIRECT=true : lognseg==0; write normalized bf16 straight to outd.
// ---------------------------------------------------------------------------
template <bool DIRECT>
__global__ __launch_bounds__(256) void flashsp_kernel(
    const short* __restrict__ q, const short* __restrict__ k,
    const short* __restrict__ vT, float* __restrict__ po,
    float* __restrict__ pm, float* __restrict__ pl,
    short* __restrict__ outd,
    int qrs, int qbrows, long kbstride, int krstride,
    int tokpb, int seglen, int lognseg) {
  __shared__ short Qs[64 * 64];
  __shared__ short Ks[64 * 64];
  __shared__ short Vs[64 * 64];
  __shared__ short Ps[64 * 72];
  int tid = threadIdx.x;
  // XCD-locality block decode
  int lin = blockIdx.x + 4 * blockIdx.y + 32 * blockIdx.z;
  int xg = lin & 7, t = lin >> 3;
  int qt = t & 3;
  int m = (t >> 2) * 8 + xg;
  int h = m & 7, bz = m >> 3;
  int b = bz >> lognseg, seg = bz & ((1 << lognseg) - 1);
  int lane = tid & 63, wv = tid >> 6;
  int g = lane >> 4, c = lane & 15;
  int srow = lane >> 3, skc = lane & 7;

#pragma unroll
  for (int gi = 0; gi < 2; ++gi) {
    int grp = wv * 2 + gi;
    int row = grp * 8 + srow;
    int sw = ((skc ^ (row & 7)) * 8);
    gload16(&Qs[grp * 512],
            &q[((size_t)(b * qbrows) + qt * 64 + row) * qrs + h * 64 + sw]);
  }

  float m_[4], l_[4];
  floatx4 zf = {0.f, 0.f, 0.f, 0.f};
  floatx4 o_[4];
#pragma unroll
  for (int r = 0; r < 4; ++r) { m_[r] = -3.0e38f; l_[r] = 0.f; }
#pragma unroll
  for (int f = 0; f < 4; ++f) o_[f] = zf;

  const short* vbase = vT + (size_t)(b * 8 + h) * 64 * tokpb;
  int tbeg = seg * seglen, tend = tbeg + seglen;
  for (int t0 = tbeg; t0 < tend; t0 += 64) {
#pragma unroll
    for (int gi = 0; gi < 2; ++gi) {
      int grp = wv * 2 + gi;
      int row = grp * 8 + srow;
      int sw = ((skc ^ (row & 7)) * 8);
      gload16(&Ks[grp * 512],
              &k[(size_t)b * kbstride + (size_t)(t0 + row) * krstride + h * 64 + sw]);
      gload16(&Vs[grp * 512], &vbase[(size_t)row * tokpb + t0 + sw]);
    }
    __syncthreads();

    floatx4 s[4];
#pragma unroll
    for (int f = 0; f < 4; ++f) s[f] = zf;
#pragma unroll
    for (int ks = 0; ks < 2; ++ks) {
      int slot = ((ks * 4 + g) ^ (c & 7)) * 8;
      short8 a = *(const short8*)&Qs[(wv * 16 + c) * 64 + slot];
#pragma unroll
      for (int f = 0; f < 4; ++f) {
        short8 b8 = *(const short8*)&Ks[(f * 16 + c) * 64 + slot];
        s[f] = mfma16(a, b8, s[f]);
      }
    }

    float nm[4], sf[4], rs[4];
#pragma unroll
    for (int r = 0; r < 4; ++r) {
      float tmax = fmaxf(fmaxf(s[0][r], s[1][r]), fmaxf(s[2][r], s[3][r]));
#pragma unroll
      for (int msk = 1; msk < 16; msk <<= 1) tmax = fmaxf(tmax, __shfl_xor(tmax, msk));
      nm[r] = fmaxf(m_[r], tmax);
      sf[r] = __expf(m_[r] - nm[r]);
      rs[r] = 0.f;
    }
#pragma unroll
    for (int f = 0; f < 4; ++f)
#pragma unroll
      for (int r = 0; r < 4; ++r) {
        float p = __expf(s[f][r] - nm[r]);
        s[f][r] = p; rs[r] += p;
      }
#pragma unroll
    for (int r = 0; r < 4; ++r) {
#pragma unroll
      for (int msk = 1; msk < 16; msk <<= 1) rs[r] += __shfl_xor(rs[r], msk);
      l_[r] = l_[r] * sf[r] + rs[r];
      m_[r] = nm[r];
    }
#pragma unroll
    for (int f = 0; f < 4; ++f)
#pragma unroll
      for (int r = 0; r < 4; ++r) o_[f][r] *= sf[r];
#pragma unroll
    for (int f = 0; f < 4; ++f)
#pragma unroll
      for (int r = 0; r < 4; ++r)
        Ps[(wv * 16 + g * 4 + r) * 72 + f * 16 + c] = f2bf(s[f][r]);
    __syncthreads();
#pragma unroll
    for (int ks = 0; ks < 2; ++ks) {
      int slot = ((ks * 4 + g) ^ (c & 7)) * 8;
      short8 pa = *(const short8*)&Ps[(wv * 16 + c) * 72 + ks * 32 + g * 8];
#pragma unroll
      for (int f = 0; f < 4; ++f) {
        short8 vb = *(const short8*)&Vs[(f * 16 + c) * 64 + slot];
        o_[f] = mfma16(pa, vb, o_[f]);
      }
    }
    __syncthreads();
  }

  if (DIRECT) {
    float il[4];
#pragma unroll
    for (int r = 0; r < 4; ++r) il[r] = 1.f / l_[r];
#pragma unroll
    for (int f = 0; f < 4; ++f)
#pragma unroll
      for (int r = 0; r < 4; ++r) {
        int row = qt * 64 + wv * 16 + g * 4 + r;
        outd[((size_t)(b * 256 + row)) * 512 + h * 64 + f * 16 + c] =
            f2bf(o_[f][r] * il[r]);
      }
  } else {
#pragma unroll
    for (int f = 0; f < 4; ++f)
#pragma unroll
      for (int r = 0; r < 4; ++r) {
        int row = qt * 64 + wv * 16 + g * 4 + r;
        size_t grow = (size_t)seg * 2048 + b * 256 + row;
        po[grow * 512 + h * 64 + f * 16 + c] = o_[f][r];
        if (f == 0 && c == 0) {
          pm[grow * 8 + h] = m_[r];
          pl[grow * 8 + h] = l_[r];
        }
      }
  }
}

// ---------------------------------------------------------------------------
// Combine NSEG partial attention results -> bf16 out [2048,512]
// ---------------------------------------------------------------------------
template <int NSEG>
__global__ __launch_bounds__(256) void fcomb_kernel(
    const float* __restrict__ po, const float* __restrict__ pm,
    const float* __restrict__ pl, short* __restrict__ out) {
  int idx = blockIdx.x * 256 + threadIdx.x;  // over 2048*512
  int grow = idx >> 9, col = idx & 511, h = col >> 6;
  float ms[NSEG];
  float M = -3.0e38f;
#pragma unroll
  for (int s = 0; s < NSEG; ++s) {
    ms[s] = pm[((size_t)s * 2048 + grow) * 8 + h];
    M = fmaxf(M, ms[s]);
  }
  float L = 0.f, acc = 0.f;
#pragma unroll
  for (int s = 0; s < NSEG; ++s) {
    float w = __expf(ms[s] - M);
    L += w * pl[((size_t)s * 2048 + grow) * 8 + h];
    acc += w * po[((size_t)s * 2048 + grow) * 512 + col];
  }
  out[idx] = f2bf(acc / L);
}

// ---------------------------------------------------------------------------
extern "C" void kernel_launch(void* const* d_in, const int* in_sizes, int n_in,
                              void* d_out, int out_size, void* d_ws, size_t ws_size,
                              hipStream_t stream) {
  const float* x       = (const float*)d_in[0];
  const float* pos     = (const float*)d_in[1];
  const float* W_pos   = (const float*)d_in[2];
  const float* b_pos   = (const float*)d_in[3];
  const float* W_in    = (const float*)d_in[4];
  const float* b_in    = (const float*)d_in[5];
  const float* latents = (const float*)d_in[6];
  const float* lnq_g   = (const float*)d_in[7];
  const float* lnq_b   = (const float*)d_in[8];
  const float* lnk_g   = (const float*)d_in[9];
  const float* lnk_b   = (const float*)d_in[10];
  const float* lnv_g   = (const float*)d_in[11];
  const float* lnv_b   = (const float*)d_in[12];
  const float* cWq     = (const float*)d_in[13];
  const float* cWk     = (const float*)d_in[14];
  const float* cWv     = (const float*)d_in[15];
  const float* cWo     = (const float*)d_in[16];
  const float* c_bo    = (const float*)d_in[17];
  const float* ln1_g   = (const float*)d_in[18];
  const float* ln1_b   = (const float*)d_in[19];
  const float* sWq     = (const float*)d_in[20];
  const float* sWkv    = (const float*)d_in[21];
  const float* sWo     = (const float*)d_in[22];
  const float* s_bo    = (const float*)d_in[23];
  const float* ln2_g   = (const float*)d_in[24];
  const float* ln2_b   = (const float*)d_in[25];
  const float* fW1     = (const float*)d_in[26];
  const float* f_b1    = (const float*)d_in[27];
  const float* fW2     = (const float*)d_in[28];
  const float* f_b2    = (const float*)d_in[29];
  const float* lnf_g   = (const float*)d_in[30];
  const float* lnf_b   = (const float*)d_in[31];
  const float* Wb      = (const float*)d_in[32];
  const float* bbv     = (const float*)d_in[33];
  float* outp = (float*)d_out;

  // bf16 transposed weight offsets (elements)
  size_t W = 0;
  size_t o_cWq = W; W += 512 * 512;
  size_t o_cWk = W; W += 512 * 512;
  size_t o_cWv = W; W += 512 * 512;
  size_t o_cWo = W; W += 512 * 512;
  size_t o_Wb  = W; W += 64 * 512;
  size_t o_Wpos = W; W += 512 * 64;
  size_t o_sQKV[6], o_sWo[6], o_fW1[6], o_fW2[6];
  for (int i = 0; i < 6; ++i) {
    o_sQKV[i] = W; W += 1536 * 512;   // q rows 0..511 (pre-scaled), k 512..1023, v 1024..1535
    o_sWo[i]  = W; W += 512 * 512;
    o_fW1[i]  = W; W += 2048 * 512;
    o_fW2[i]  = W; W += 512 * 2048;
  }
  MatTable T;
  int nm = 0;
  auto add = [&](const float* s, int K, int N, int kp, size_t off, float sc) {
    T.m[nm].src = s; T.m[nm].K = K; T.m[nm].N = N; T.m[nm].kp = kp;
    T.m[nm].off = (int)off; T.m[nm].scale = sc; ++nm;
  };
  const float SC = 0.125f;  // DH^-0.5 folded into Wq
  add(cWq, 512, 512, 512, o_cWq, SC); add(cWk, 512, 512, 512, o_cWk, 1.f);
  add(cWv, 512, 512, 512, o_cWv, 1.f); add(cWo, 512, 512, 512, o_cWo, 1.f);
  add(Wb, 512, 64, 512, o_Wb, 1.f);
  add(W_pos, 48, 512, 64, o_Wpos, 1.f);
  for (int i = 0; i < 6; ++i) {
    add(sWq  + (size_t)i * 512 * 512,  512, 512,  512, o_sQKV[i], SC);
    add(sWkv + (size_t)i * 512 * 1024, 512, 1024, 512, o_sQKV[i] + 512 * 512, 1.f);
    add(sWo  + (size_t)i * 512 * 512,  512, 512,  512, o_sWo[i], 1.f);
    add(fW1  + (size_t)i * 512 * 2048, 512, 2048, 512, o_fW1[i], 1.f);
    add(fW2  + (size_t)i * 2048 * 512, 2048, 512, 2048, o_fW2[i], 1.f);
  }

  // workspace carve
  char* p = (char*)d_ws;
  auto carve = [&](size_t bytes) {
    char* r = p; p += (bytes + 255) & ~(size_t)255; return r;
  };
  short* wtb   = (short*)carve(W * 2);                     // ~40MB
  short* enc   = (short*)carve((size_t)32768 * 64 * 2);    // 4MB
  short* knvn  = (short*)carve((size_t)32768 * 1024 * 2);  // 64MB  [k | v]
  short* kc    = (short*)carve((size_t)32768 * 512 * 2);   // 32MB K proj
  short* vTc   = (short*)carve((size_t)32768 * 512 * 2);   // 32MB V^T proj [b][h][64][4096]
  short* latn0 = (short*)carve(262144);
  short* qc    = (short*)carve(262144);
  float* lat   = (float*)carve(4194304);
  float* pm    = (float*)carve(1048576);
  float* pl    = (float*)carve(1048576);
  // aliases into dead regions:
  short* attno = enc;                                  // enc dead after embed2
  float* po    = (float*)knvn;                         // knvn dead after projections (32MB used)
  short* h     = (short*)((char*)knvn + 36 * 1048576); // 2MB
  short* qkv   = (short*)((char*)knvn + 40 * 1048576); // [2048][1024] q|k = 4MB
  short* ffh   = (short*)((char*)knvn + 48 * 1048576); // 8MB
  short* vTs   = (short*)((char*)knvn + 58 * 1048576); // [8][8][64][256] = 2MB

  wtrans_kernel<<<dim3(1024, 36), 256, 0, stream>>>(T, wtb);
  enc_kernel<<<1024, 256, 0, stream>>>(pos, enc);
  embed2_kernel<<<256, 512, 0, stream>>>(enc, wtb + o_Wpos, b_pos, W_in, b_in, x,
                                         lnk_g, lnk_b, lnv_g, lnv_b, knvn);
  ln_kernel<<<64, 256, 0, stream>>>(latents, lnq_g, lnq_b, latn0, 256);
  gemm64_kernel<0><<<dim3(8, 4), 256, 0, stream>>>(latn0, wtb + o_cWq, nullptr, qc, 256, 512, 512, 512, 512, nullptr);
  gemm_kernel<0><<<dim3(4, 256), 256, 0, stream>>>(knvn, wtb + o_cWk, nullptr, kc, 32768, 512, 512, 1024, 512, nullptr, 0, 0);
  gemm_kernel<0><<<dim3(4, 256), 256, 0, stream>>>(knvn + 512, wtb + o_cWv, nullptr, nullptr, 32768, 512, 512, 1024, 512, vTc, 0, 4096);
  // cross attention: 8 KV segments of 512 tokens; qc shared across b (qbrows=0)
  flashsp_kernel<false><<<dim3(4, 8, 64), 256, 0, stream>>>(qc, kc, vTc, po, pm, pl,
                                                            nullptr, 512, 0,
                                                            (long)4096 * 512, 512, 4096, 512, 3);
  fcomb_kernel<8><<<4096, 256, 0, stream>>>(po, pm, pl, attno);
  // lat = bcast(latents) + attno @ cWo + c_bo   (EPI=4 folds the broadcast)
  gemm64_kernel<4><<<dim3(8, 32), 256, 0, stream>>>(attno, wtb + o_cWo, c_bo, lat, 2048, 512, 512, 512, 512, latents);

  for (int i = 0; i < 6; ++i) {
    ln_kernel<<<512, 256, 0, stream>>>(lat, ln1_g + i * 512, ln1_b + i * 512, h, 2048);
    // q|k -> qkv [2048][1024]; v -> vTs (transposed epilogue, bcol>=1024)
    gemm_kernel<0><<<dim3(12, 16), 256, 0, stream>>>(h, wtb + o_sQKV[i], nullptr, qkv, 2048, 1536, 512, 512, 1024, vTs, 1024, 256);
    // self attention: no split, direct normalized bf16 output (per-batch q)
    flashsp_kernel<true><<<dim3(4, 8, 8), 256, 0, stream>>>(qkv, qkv + 512, vTs,
                                                            nullptr, nullptr, nullptr, attno,
                                                            1024, 256, (long)256 * 1024, 1024, 256, 256, 0);
    gemm64_kernel<2><<<dim3(8, 32), 256, 0, stream>>>(attno, wtb + o_sWo[i], s_bo + i * 512, lat, 2048, 512, 512, 512, 512, nullptr);
    ln_kernel<<<512, 256, 0, stream>>>(lat, ln2_g + i * 512, ln2_b + i * 512, h, 2048);
    gemm_kernel<1><<<dim3(16, 16), 256, 0, stream>>>(h, wtb + o_fW1[i], f_b1 + i * 2048, ffh, 2048, 2048, 512, 512, 2048, nullptr, 0, 0);
    gemm64_kernel<2><<<dim3(8, 32), 256, 0, stream>>>(ffh, wtb + o_fW2[i], f_b2 + i * 512, lat, 2048, 512, 2048, 2048, 512, nullptr);
  }
  ln_kernel<<<512, 256, 0, stream>>>(lat, lnf_g, lnf_b, h, 2048);
  gemm64_kernel<3><<<dim3(1, 32), 256, 0, stream>>>(h, wtb + o_Wb, bbv, outp, 2048, 64, 512, 512, 64, nullptr);
}

// Round 10
// 816.371 us; speedup vs baseline: 1.0115x; 1.0096x over previous
//
#include <hip/hip_runtime.h>
#include <hip/hip_bf16.h>

#define DEV __device__ __forceinline__

typedef __attribute__((ext_vector_type(8))) short short8;
typedef __attribute__((ext_vector_type(4))) float floatx4;

DEV short f2bf(float f) {
  unsigned u = __float_as_uint(f);
  u += 0x7fffu + ((u >> 16) & 1u);
  return (short)(u >> 16);
}
DEV float bf2f(short s) {
  return __uint_as_float(((unsigned)(unsigned short)s) << 16);
}
DEV float wred(float v) {
#pragma unroll
  for (int m = 1; m < 64; m <<= 1) v += __shfl_xor(v, m);
  return v;
}
DEV floatx4 mfma16(short8 a, short8 b, floatx4 c) {
  return __builtin_amdgcn_mfma_f32_16x16x32_bf16(a, b, c, 0, 0, 0);
}
// async global->LDS, 16B per lane, dest = wave-uniform base + lane*16
DEV void gload16(void* lds, const void* g) {
  __builtin_amdgcn_global_load_lds(
      (const __attribute__((address_space(1))) unsigned int*)g,
      (__attribute__((address_space(3))) unsigned int*)lds, 16, 0, 0);
}

// ---------------------------------------------------------------------------
// Weight transpose+convert+scale: src fp32 [K,N] -> dst bf16 [N][kp]
// ---------------------------------------------------------------------------
struct MatDesc { const float* src; int K; int N; int kp; int off; float scale; };
struct MatTable { MatDesc m[36]; };

__global__ __launch_bounds__(256) void wtrans_kernel(MatTable T, short* __restrict__ dst) {
  int mi = blockIdx.y;
  MatDesc d = T.m[mi];
  int tilesx = d.N >> 5, tilesy = d.kp >> 5;
  int tb = blockIdx.x;
  if (tb >= tilesx * tilesy) return;
  int ty = tb / tilesx, tx = tb % tilesx;
  __shared__ float tile[32][33];
  int tid = threadIdx.x;
#pragma unroll
  for (int i = 0; i < 4; ++i) {
    int e = tid + i * 256, lr = e >> 5, lc = e & 31;
    int kk = ty * 32 + lr;
    tile[lr][lc] = (kk < d.K) ? d.src[(size_t)kk * d.N + tx * 32 + lc] : 0.f;
  }
  __syncthreads();
#pragma unroll
  for (int i = 0; i < 4; ++i) {
    int e = tid + i * 256, lr = e >> 5, lc = e & 31;
    dst[(size_t)d.off + (size_t)(tx * 32 + lr) * d.kp + ty * 32 + lc] =
        f2bf(tile[lc][lr] * d.scale);
  }
}

// ---------------------------------------------------------------------------
// Fused NeRF enc + pos-embed GEMM (K=64) + relu + x@W_in + LN(k), LN(v)
// 512 threads = 8 waves; block = 128 rows; params staged in LDS; enc computed
// in registers straight into El (no enc kernel / global round-trip).
// Output: knvn [32768][1024], LN(k) cols 0..511, LN(v) cols 512..1023.
// ---------------------------------------------------------------------------
__global__ __launch_bounds__(512) void embed2_kernel(
    const float* __restrict__ pos, const short* __restrict__ Wt,  // [512][64]
    const float* __restrict__ b_pos, const float* __restrict__ W_in,
    const float* __restrict__ b_in, const float* __restrict__ x,
    const float* __restrict__ lnk_g, const float* __restrict__ lnk_b,
    const float* __restrict__ lnv_g, const float* __restrict__ lnv_b,
    short* __restrict__ knvn) {
  __shared__ short Wl[512 * 64];   // 64 KB
  __shared__ short El[128 * 64];   // 16 KB
  __shared__ float Pf[9 * 512];    // 18 KB params
  int tid = threadIdx.x;
  int lane = tid & 63, wv = tid >> 6;
  int c = lane & 15, g = lane >> 4;
  int blk = blockIdx.x * 128;
#pragma unroll
  for (int gi = 0; gi < 8; ++gi) {
    int grp = wv * 8 + gi;
    int row = grp * 8 + (lane >> 3), kc = lane & 7;
    gload16(&Wl[grp * 512], &Wt[(size_t)row * 64 + ((kc ^ (row & 7)) * 8)]);
  }
  // NeRF enc computed in-register -> El (swizzled, same layout as gload path)
#pragma unroll
  for (int ci = 0; ci < 2; ++ci) {
    int ch = ci * 512 + tid;       // 1024 chunks = 128 rows x 8 kc-groups
    int row = ch >> 3, kc = ch & 7;
    float p0 = pos[(size_t)(blk + row) * 2];
    float p1 = pos[(size_t)(blk + row) * 2 + 1];
    short8 o;
#pragma unroll
    for (int j = 0; j < 8; ++j) {
      int kk2 = kc * 8 + j;
      float val = 0.f;
      if (kk2 < 48) {
        int dd = kk2 / 24, rem = kk2 % 24;
        int trig = rem / 12, f = rem % 12;
        float ang = (dd ? p1 : p0) * exp2f((4.0f / 11.0f) * (float)f);
        val = trig ? __cosf(ang) : __sinf(ang);
      }
      o[j] = f2bf(val);
    }
    *(short8*)&El[row * 64 + ((kc ^ (row & 7)) * 8)] = o;
  }
  Pf[tid]        = b_pos[tid];
  Pf[512 + tid]  = W_in[tid];
  Pf[1024 + tid] = W_in[512 + tid];
  Pf[1536 + tid] = W_in[1024 + tid];
  Pf[2048 + tid] = b_in[tid];
  Pf[2560 + tid] = lnk_g[tid];
  Pf[3072 + tid] = lnk_b[tid];
  Pf[3584 + tid] = lnv_g[tid];
  Pf[4096 + tid] = lnv_b[tid];
  __syncthreads();

  floatx4 acc[32];
  floatx4 zf = {0.f, 0.f, 0.f, 0.f};
#pragma unroll
  for (int nf = 0; nf < 32; ++nf) acc[nf] = zf;
  short8 af[2];
#pragma unroll
  for (int ks = 0; ks < 2; ++ks)
    af[ks] = *(const short8*)&El[(wv * 16 + c) * 64 + ((ks * 4 + g) ^ (c & 7)) * 8];
#pragma unroll
  for (int nf = 0; nf < 32; ++nf) {
#pragma unroll
    for (int ks = 0; ks < 2; ++ks) {
      short8 bf8 = *(const short8*)&Wl[(nf * 16 + c) * 64 + ((ks * 4 + g) ^ (c & 7)) * 8];
      acc[nf] = mfma16(af[ks], bf8, acc[nf]);
    }
  }

  int rowbase = blk + wv * 16 + g * 4;
  float x0[4], x1[4], x2[4];
  float s1[4], q1[4], s2[4], q2[4];
#pragma unroll
  for (int r = 0; r < 4; ++r) {
    x0[r] = x[(size_t)(rowbase + r) * 3];
    x1[r] = x[(size_t)(rowbase + r) * 3 + 1];
    x2[r] = x[(size_t)(rowbase + r) * 3 + 2];
    s1[r] = 0; q1[r] = 0; s2[r] = 0; q2[r] = 0;
  }
#pragma unroll
  for (int nf = 0; nf < 32; ++nf) {
    int col = nf * 16 + c;
    float bp = Pf[col];
    float w0 = Pf[512 + col], w1 = Pf[1024 + col], w2 = Pf[1536 + col], bi = Pf[2048 + col];
#pragma unroll
    for (int r = 0; r < 4; ++r) {
      float kk = fmaxf(acc[nf][r] + bp, 0.f);
      float vv = kk + x0[r] * w0 + x1[r] * w1 + x2[r] * w2 + bi;
      acc[nf][r] = kk;
      s1[r] += kk; q1[r] += kk * kk; s2[r] += vv; q2[r] += vv * vv;
    }
  }
  float m1[4], r1[4], m2[4], r2[4];
#pragma unroll
  for (int r = 0; r < 4; ++r) {
#pragma unroll
    for (int msk = 1; msk < 16; msk <<= 1) {
      s1[r] += __shfl_xor(s1[r], msk); q1[r] += __shfl_xor(q1[r], msk);
      s2[r] += __shfl_xor(s2[r], msk); q2[r] += __shfl_xor(q2[r], msk);
    }
    m1[r] = s1[r] * (1.f / 512.f);
    r1[r] = rsqrtf(q1[r] * (1.f / 512.f) - m1[r] * m1[r] + 1e-5f);
    m2[r] = s2[r] * (1.f / 512.f);
    r2[r] = rsqrtf(q2[r] * (1.f / 512.f) - m2[r] * m2[r] + 1e-5f);
  }
#pragma unroll
  for (int nf = 0; nf < 32; ++nf) {
    int col = nf * 16 + c;
    float w0 = Pf[512 + col], w1 = Pf[1024 + col], w2 = Pf[1536 + col], bi = Pf[2048 + col];
    float gk = Pf[2560 + col], bk = Pf[3072 + col];
    float gv = Pf[3584 + col], bv = Pf[4096 + col];
#pragma unroll
    for (int r = 0; r < 4; ++r) {
      float kk = acc[nf][r];
      float vv = kk + x0[r] * w0 + x1[r] * w1 + x2[r] * w2 + bi;
      size_t ridx = (size_t)(rowbase + r) * 1024;
      knvn[ridx + col] = f2bf((kk - m1[r]) * r1[r] * gk + bk);
      knvn[ridx + 512 + col] = f2bf((vv - m2[r]) * r2[r] * gv + bv);
    }
  }
}

// ---------------------------------------------------------------------------
// LayerNorm fp32 in [M,512] -> bf16 out, one wave per row
// ---------------------------------------------------------------------------
__global__ __launch_bounds__(256) void ln_kernel(
    const float* __restrict__ in, const float* __restrict__ g,
    const float* __restrict__ b, short* __restrict__ out, int M) {
  int row = blockIdx.x * 4 + (threadIdx.x >> 6);
  if (row >= M) return;
  int lane = threadIdx.x & 63;
  float v[8]; float s = 0, q = 0;
#pragma unroll
  for (int j = 0; j < 8; ++j) {
    v[j] = in[(size_t)row * 512 + lane + 64 * j];
    s += v[j]; q += v[j] * v[j];
  }
  s = wred(s); q = wred(q);
  float m = s * (1.f / 512.f);
  float rs = rsqrtf(q * (1.f / 512.f) - m * m + 1e-5f);
#pragma unroll
  for (int j = 0; j < 8; ++j) {
    int cc = lane + 64 * j;
    out[(size_t)row * 512 + cc] = f2bf((v[j] - m) * rs * g[cc] + b[cc]);
  }
}

// ---------------------------------------------------------------------------
// Shared GEMM epilogue op
// EPI: 0 = bf16 out, 1 = gelu->bf16, 2 = fp32 residual +=, 3 = fp32 out
// ---------------------------------------------------------------------------
template <int EPI>
DEV void epi_store(void* outp, size_t idx, float xv) {
  if (EPI == 0) {
    ((short*)outp)[idx] = f2bf(xv);
  } else if (EPI == 1) {
    float t = 0.7978845608f * (xv + 0.044715f * xv * xv * xv);
    ((short*)outp)[idx] = f2bf(0.5f * xv * (1.f + tanhf(t)));
  } else if (EPI == 2) {
    ((float*)outp)[idx] += xv;
  } else if (EPI == 3) {
    ((float*)outp)[idx] = xv;
  }
}

// ---------------------------------------------------------------------------
// GEMM 128x128 tile, BK=64, 4 waves (2x2). A bf16 [M,*lda]; Wt bf16 [N][K].
// XCD-aware block swizzle (requires gridDim.x*gridDim.y % 8 == 0).
// Optional transposed-V epilogue: blocks with bcol >= vcol0 write C^T into
// vT[b][h][d][tok] (tokpb tokens per (b,h)).
// ---------------------------------------------------------------------------
template <int EPI>
__global__ __launch_bounds__(256) void gemm_kernel(
    const short* __restrict__ A, const short* __restrict__ Wt,
    const float* __restrict__ bias, void* __restrict__ outp,
    int M, int N, int K, int lda, int ldo,
    short* __restrict__ vT, int vcol0, int tokpb) {
  __shared__ short SL[16384];  // Alds | Blds union; reused for C^T staging
  short* Alds = SL;
  short* Blds = SL + 8192;
  int tid = threadIdx.x;
  int nwg = gridDim.x * gridDim.y;
  int id = blockIdx.y * gridDim.x + blockIdx.x;
  int cpx = nwg >> 3;
  id = (id & 7) * cpx + (id >> 3);
  int brow = (id / gridDim.x) * 128, bcol = (id % gridDim.x) * 128;
  int lane = tid & 63, wvid = tid >> 6;
  int wr = wvid >> 1, wc = wvid & 1;
  int g = lane >> 4, c = lane & 15;
  floatx4 zf = {0.f, 0.f, 0.f, 0.f};
  floatx4 acc[4][4];
#pragma unroll
  for (int i = 0; i < 4; ++i)
#pragma unroll
    for (int j = 0; j < 4; ++j) acc[i][j] = zf;

  int srow = (lane >> 3), skc = lane & 7;
  for (int k0 = 0; k0 < K; k0 += 64) {
#pragma unroll
    for (int gi = 0; gi < 4; ++gi) {
      int grp = wvid * 4 + gi;
      int row = grp * 8 + srow;
      int sw = ((skc ^ (row & 7)) * 8);
      gload16(&Alds[grp * 512], &A[(size_t)(brow + row) * lda + k0 + sw]);
      gload16(&Blds[grp * 512], &Wt[(size_t)(bcol + row) * K + k0 + sw]);
    }
    __syncthreads();
#pragma unroll
    for (int ks = 0; ks < 2; ++ks) {
      int slot = ((ks * 4 + g) ^ (c & 7)) * 8;
      short8 af[4], bf8[4];
#pragma unroll
      for (int mf = 0; mf < 4; ++mf)
        af[mf] = *(const short8*)&Alds[(wr * 64 + mf * 16 + c) * 64 + slot];
#pragma unroll
      for (int nf = 0; nf < 4; ++nf)
        bf8[nf] = *(const short8*)&Blds[(wc * 64 + nf * 16 + c) * 64 + slot];
#pragma unroll
      for (int mf = 0; mf < 4; ++mf)
#pragma unroll
        for (int nf = 0; nf < 4; ++nf)
          acc[mf][nf] = mfma16(af[mf], bf8[nf], acc[mf][nf]);
    }
    __syncthreads();
  }

  if (vT != nullptr && bcol >= vcol0) {
#pragma unroll
    for (int half = 0; half < 2; ++half) {
      __syncthreads();
      if (wr == half) {
#pragma unroll
        for (int mf = 0; mf < 4; ++mf)
#pragma unroll
          for (int nf = 0; nf < 4; ++nf) {
            int lcol = wc * 64 + nf * 16 + c;
            int lrow = mf * 16 + g * 4;
#pragma unroll
            for (int r = 0; r < 4; ++r)
              SL[lcol * 66 + lrow + r] = f2bf(acc[mf][nf][r]);
          }
      }
      __syncthreads();
      int gr = brow + half * 64;
      int bb = gr / tokpb, tok0 = gr % tokpb;
#pragma unroll
      for (int it = 0; it < 2; ++it) {
        int e = it * 256 + tid;
        int colrow = e >> 2, t16 = (e & 3) * 16;
        int hd = bcol + colrow - vcol0;
        short* dst = vT + ((size_t)(bb * 8 + (hd >> 6)) * 64 + (hd & 63)) * tokpb + tok0 + t16;
        *(short8*)dst = *(const short8*)&SL[colrow * 66 + t16];
        *(short8*)(dst + 8) = *(const short8*)&SL[colrow * 66 + t16 + 8];
      }
    }
    return;
  }

#pragma unroll
  for (int mf = 0; mf < 4; ++mf) {
#pragma unroll
    for (int nf = 0; nf < 4; ++nf) {
      int col = bcol + wc * 64 + nf * 16 + c;
      float bv = bias ? bias[col] : 0.f;
      int row0 = brow + wr * 64 + mf * 16 + g * 4;
#pragma unroll
      for (int r = 0; r < 4; ++r)
        epi_store<EPI>(outp, (size_t)(row0 + r) * ldo + col, acc[mf][nf][r] + bv);
    }
  }
}

// ---------------------------------------------------------------------------
// GEMM 64x64 tile. 4 waves (2x2), each wave 32x32. XCD swizzle (grid%8==0).
// EPI==4 uses lat0 (latents broadcast source).
// ---------------------------------------------------------------------------
template <int EPI>
__global__ __launch_bounds__(256) void gemm64_kernel(
    const short* __restrict__ A, const short* __restrict__ Wt,
    const float* __restrict__ bias, void* __restrict__ outp,
    int M, int N, int K, int lda, int ldo, const float* __restrict__ lat0) {
  __shared__ short Alds[64 * 64];
  __shared__ short Blds[64 * 64];
  int tid = threadIdx.x;
  int nwg = gridDim.x * gridDim.y;
  int id = blockIdx.y * gridDim.x + blockIdx.x;
  int cpx = nwg >> 3;
  id = (id & 7) * cpx + (id >> 3);
  int brow = (id / gridDim.x) * 64, bcol = (id % gridDim.x) * 64;
  int lane = tid & 63, wvid = tid >> 6;
  int wr = wvid >> 1, wc = wvid & 1;
  int g = lane >> 4, c = lane & 15;
  floatx4 zf = {0.f, 0.f, 0.f, 0.f};
  floatx4 acc[2][2];
#pragma unroll
  for (int i = 0; i < 2; ++i)
#pragma unroll
    for (int j = 0; j < 2; ++j) acc[i][j] = zf;

  int srow = (lane >> 3), skc = lane & 7;
  for (int k0 = 0; k0 < K; k0 += 64) {
#pragma unroll
    for (int gi = 0; gi < 2; ++gi) {
      int grp = wvid * 2 + gi;
      int row = grp * 8 + srow;
      int sw = ((skc ^ (row & 7)) * 8);
      gload16(&Alds[grp * 512], &A[(size_t)(brow + row) * lda + k0 + sw]);
      gload16(&Blds[grp * 512], &Wt[(size_t)(bcol + row) * K + k0 + sw]);
    }
    __syncthreads();
#pragma unroll
    for (int ks = 0; ks < 2; ++ks) {
      int slot = ((ks * 4 + g) ^ (c & 7)) * 8;
      short8 af[2], bf8[2];
#pragma unroll
      for (int mf = 0; mf < 2; ++mf)
        af[mf] = *(const short8*)&Alds[(wr * 32 + mf * 16 + c) * 64 + slot];
#pragma unroll
      for (int nf = 0; nf < 2; ++nf)
        bf8[nf] = *(const short8*)&Blds[(wc * 32 + nf * 16 + c) * 64 + slot];
#pragma unroll
      for (int mf = 0; mf < 2; ++mf)
#pragma unroll
        for (int nf = 0; nf < 2; ++nf)
          acc[mf][nf] = mfma16(af[mf], bf8[nf], acc[mf][nf]);
    }
    __syncthreads();
  }

#pragma unroll
  for (int mf = 0; mf < 2; ++mf) {
#pragma unroll
    for (int nf = 0; nf < 2; ++nf) {
      int col = bcol + wc * 32 + nf * 16 + c;
      float bv = bias ? bias[col] : 0.f;
      int row0 = brow + wr * 32 + mf * 16 + g * 4;
#pragma unroll
      for (int r = 0; r < 4; ++r) {
        float xv = acc[mf][nf][r] + bv;
        size_t idx = (size_t)(row0 + r) * ldo + col;
        if (EPI == 4) {
          ((float*)outp)[idx] = lat0[(size_t)((row0 + r) & 255) * 512 + col] + xv;
        } else {
          epi_store<EPI>(outp, idx, xv);
        }
      }
    }
  }
}

// ---------------------------------------------------------------------------
// Split-KV flash attention, 64-row Q tile, 4 waves, KVBLK=128 (2 subtiles
// staged per barrier round). Q pre-scaled by DH^-0.5 * log2(e) -> softmax in
// exp2 domain. V supplied TRANSPOSED: vT[b][h][d][tok]. XCD-locality decode.
// DIRECT=false: write unnormalized partial O fp32 + m,l (log2-domain m).
// DIRECT=true : lognseg==0; write normalized bf16 straight to outd.
// seglen must be a multiple of 128.
// ---------------------------------------------------------------------------
template <bool DIRECT>
__global__ __launch_bounds__(256) void flashsp_kernel(
    const short* __restrict__ q, const short* __restrict__ k,
    const short* __restrict__ vT, float* __restrict__ po,
    float* __restrict__ pm, float* __restrict__ pl,
    short* __restrict__ outd,
    int qrs, int qbrows, long kbstride, int krstride,
    int tokpb, int seglen, int lognseg) {
  __shared__ short Qs[64 * 64];
  __shared__ short Ks[2 * 64 * 64];
  __shared__ short Vs[2 * 64 * 64];
  __shared__ short Ps[64 * 72];
  int tid = threadIdx.x;
  // XCD-locality block decode
  int lin = blockIdx.x + 4 * blockIdx.y + 32 * blockIdx.z;
  int xg = lin & 7, t = lin >> 3;
  int qt = t & 3;
  int m = (t >> 2) * 8 + xg;
  int h = m & 7, bz = m >> 3;
  int b = bz >> lognseg, seg = bz & ((1 << lognseg) - 1);
  int lane = tid & 63, wv = tid >> 6;
  int g = lane >> 4, c = lane & 15;
  int srow = lane >> 3, skc = lane & 7;

#pragma unroll
  for (int gi = 0; gi < 2; ++gi) {
    int grp = wv * 2 + gi;
    int row = grp * 8 + srow;
    int sw = ((skc ^ (row & 7)) * 8);
    gload16(&Qs[grp * 512],
            &q[((size_t)(b * qbrows) + qt * 64 + row) * qrs + h * 64 + sw]);
  }

  float m_[4], l_[4];
  floatx4 zf = {0.f, 0.f, 0.f, 0.f};
  floatx4 o_[4];
#pragma unroll
  for (int r = 0; r < 4; ++r) { m_[r] = -3.0e38f; l_[r] = 0.f; }
#pragma unroll
  for (int f = 0; f < 4; ++f) o_[f] = zf;

  const short* vbase = vT + (size_t)(b * 8 + h) * 64 * tokpb;
  int tbeg = seg * seglen, tend = tbeg + seglen;
  for (int t0 = tbeg; t0 < tend; t0 += 128) {
    // stage 2 K subtiles + 2 V subtiles (4 gloads each per wave)
#pragma unroll
    for (int gi = 0; gi < 4; ++gi) {
      int grp16 = wv * 4 + gi;
      int sub = grp16 >> 3, grp = grp16 & 7;
      int row = grp * 8 + srow;
      int sw = ((skc ^ (row & 7)) * 8);
      gload16(&Ks[sub * 4096 + grp * 512],
              &k[(size_t)b * kbstride + (size_t)(t0 + sub * 64 + row) * krstride + h * 64 + sw]);
      gload16(&Vs[sub * 4096 + grp * 512],
              &vbase[(size_t)row * tokpb + t0 + sub * 64 + sw]);
    }
    __syncthreads();

#pragma unroll
    for (int sub = 0; sub < 2; ++sub) {
      const short* Kss = &Ks[sub * 4096];
      const short* Vss = &Vs[sub * 4096];
      floatx4 s[4];
#pragma unroll
      for (int f = 0; f < 4; ++f) s[f] = zf;
#pragma unroll
      for (int ks = 0; ks < 2; ++ks) {
        int slot = ((ks * 4 + g) ^ (c & 7)) * 8;
        short8 a = *(const short8*)&Qs[(wv * 16 + c) * 64 + slot];
#pragma unroll
        for (int f = 0; f < 4; ++f) {
          short8 b8 = *(const short8*)&Kss[(f * 16 + c) * 64 + slot];
          s[f] = mfma16(a, b8, s[f]);
        }
      }

      float nm[4], sf[4], rs[4];
#pragma unroll
      for (int r = 0; r < 4; ++r) {
        float tmax = fmaxf(fmaxf(s[0][r], s[1][r]), fmaxf(s[2][r], s[3][r]));
#pragma unroll
        for (int msk = 1; msk < 16; msk <<= 1) tmax = fmaxf(tmax, __shfl_xor(tmax, msk));
        nm[r] = fmaxf(m_[r], tmax);
        sf[r] = exp2f(m_[r] - nm[r]);
        rs[r] = 0.f;
      }
#pragma unroll
      for (int f = 0; f < 4; ++f)
#pragma unroll
        for (int r = 0; r < 4; ++r) {
          float p = exp2f(s[f][r] - nm[r]);
          s[f][r] = p; rs[r] += p;
        }
#pragma unroll
      for (int r = 0; r < 4; ++r) {
#pragma unroll
        for (int msk = 1; msk < 16; msk <<= 1) rs[r] += __shfl_xor(rs[r], msk);
        l_[r] = l_[r] * sf[r] + rs[r];
        m_[r] = nm[r];
      }
#pragma unroll
      for (int f = 0; f < 4; ++f)
#pragma unroll
        for (int r = 0; r < 4; ++r) o_[f][r] *= sf[r];
#pragma unroll
      for (int f = 0; f < 4; ++f)
#pragma unroll
        for (int r = 0; r < 4; ++r)
          Ps[(wv * 16 + g * 4 + r) * 72 + f * 16 + c] = f2bf(s[f][r]);
      __syncthreads();
#pragma unroll
      for (int ks = 0; ks < 2; ++ks) {
        int slot = ((ks * 4 + g) ^ (c & 7)) * 8;
        short8 pa = *(const short8*)&Ps[(wv * 16 + c) * 72 + ks * 32 + g * 8];
#pragma unroll
        for (int f = 0; f < 4; ++f) {
          short8 vb = *(const short8*)&Vss[(f * 16 + c) * 64 + slot];
          o_[f] = mfma16(pa, vb, o_[f]);
        }
      }
      __syncthreads();
    }
  }

  if (DIRECT) {
    float il[4];
#pragma unroll
    for (int r = 0; r < 4; ++r) il[r] = 1.f / l_[r];
#pragma unroll
    for (int f = 0; f < 4; ++f)
#pragma unroll
      for (int r = 0; r < 4; ++r) {
        int row = qt * 64 + wv * 16 + g * 4 + r;
        outd[((size_t)(b * 256 + row)) * 512 + h * 64 + f * 16 + c] =
            f2bf(o_[f][r] * il[r]);
      }
  } else {
#pragma unroll
    for (int f = 0; f < 4; ++f)
#pragma unroll
      for (int r = 0; r < 4; ++r) {
        int row = qt * 64 + wv * 16 + g * 4 + r;
        size_t grow = (size_t)seg * 2048 + b * 256 + row;
        po[grow * 512 + h * 64 + f * 16 + c] = o_[f][r];
        if (f == 0 && c == 0) {
          pm[grow * 8 + h] = m_[r];
          pl[grow * 8 + h] = l_[r];
        }
      }
  }
}

// ---------------------------------------------------------------------------
// Combine NSEG partial attention results (log2-domain m) -> bf16 out [2048,512]
// ---------------------------------------------------------------------------
template <int NSEG>
__global__ __launch_bounds__(256) void fcomb_kernel(
    const float* __restrict__ po, const float* __restrict__ pm,
    const float* __restrict__ pl, short* __restrict__ out) {
  int idx = blockIdx.x * 256 + threadIdx.x;  // over 2048*512
  int grow = idx >> 9, col = idx & 511, h = col >> 6;
  float ms[NSEG];
  float M = -3.0e38f;
#pragma unroll
  for (int s = 0; s < NSEG; ++s) {
    ms[s] = pm[((size_t)s * 2048 + grow) * 8 + h];
    M = fmaxf(M, ms[s]);
  }
  float L = 0.f, acc = 0.f;
#pragma unroll
  for (int s = 0; s < NSEG; ++s) {
    float w = exp2f(ms[s] - M);
    L += w * pl[((size_t)s * 2048 + grow) * 8 + h];
    acc += w * po[((size_t)s * 2048 + grow) * 512 + col];
  }
  out[idx] = f2bf(acc / L);
}

// ---------------------------------------------------------------------------
extern "C" void kernel_launch(void* const* d_in, const int* in_sizes, int n_in,
                              void* d_out, int out_size, void* d_ws, size_t ws_size,
                              hipStream_t stream) {
  const float* x       = (const float*)d_in[0];
  const float* pos     = (const float*)d_in[1];
  const float* W_pos   = (const float*)d_in[2];
  const float* b_pos   = (const float*)d_in[3];
  const float* W_in    = (const float*)d_in[4];
  const float* b_in    = (const float*)d_in[5];
  const float* latents = (const float*)d_in[6];
  const float* lnq_g   = (const float*)d_in[7];
  const float* lnq_b   = (const float*)d_in[8];
  const float* lnk_g   = (const float*)d_in[9];
  const float* lnk_b   = (const float*)d_in[10];
  const float* lnv_g   = (const float*)d_in[11];
  const float* lnv_b   = (const float*)d_in[12];
  const float* cWq     = (const float*)d_in[13];
  const float* cWk     = (const float*)d_in[14];
  const float* cWv     = (const float*)d_in[15];
  const float* cWo     = (const float*)d_in[16];
  const float* c_bo    = (const float*)d_in[17];
  const float* ln1_g   = (const float*)d_in[18];
  const float* ln1_b   = (const float*)d_in[19];
  const float* sWq     = (const float*)d_in[20];
  const float* sWkv    = (const float*)d_in[21];
  const float* sWo     = (const float*)d_in[22];
  const float* s_bo    = (const float*)d_in[23];
  const float* ln2_g   = (const float*)d_in[24];
  const float* ln2_b   = (const float*)d_in[25];
  const float* fW1     = (const float*)d_in[26];
  const float* f_b1    = (const float*)d_in[27];
  const float* fW2     = (const float*)d_in[28];
  const float* f_b2    = (const float*)d_in[29];
  const float* lnf_g   = (const float*)d_in[30];
  const float* lnf_b   = (const float*)d_in[31];
  const float* Wb      = (const float*)d_in[32];
  const float* bbv     = (const float*)d_in[33];
  float* outp = (float*)d_out;

  // bf16 transposed weight offsets (elements)
  size_t W = 0;
  size_t o_cWq = W; W += 512 * 512;
  size_t o_cWk = W; W += 512 * 512;
  size_t o_cWv = W; W += 512 * 512;
  size_t o_cWo = W; W += 512 * 512;
  size_t o_Wb  = W; W += 64 * 512;
  size_t o_Wpos = W; W += 512 * 64;
  size_t o_sQKV[6], o_sWo[6], o_fW1[6], o_fW2[6];
  for (int i = 0; i < 6; ++i) {
    o_sQKV[i] = W; W += 1536 * 512;   // q 0..511 (pre-scaled), k 512..1023, v 1024..1535
    o_sWo[i]  = W; W += 512 * 512;
    o_fW1[i]  = W; W += 2048 * 512;
    o_fW2[i]  = W; W += 512 * 2048;
  }
  MatTable T;
  int nm = 0;
  auto add = [&](const float* s, int K, int N, int kp, size_t off, float sc) {
    T.m[nm].src = s; T.m[nm].K = K; T.m[nm].N = N; T.m[nm].kp = kp;
    T.m[nm].off = (int)off; T.m[nm].scale = sc; ++nm;
  };
  // DH^-0.5 * log2(e) folded into Wq (softmax runs in exp2 domain)
  const float SC = 0.125f * 1.44269504088896f;
  add(cWq, 512, 512, 512, o_cWq, SC); add(cWk, 512, 512, 512, o_cWk, 1.f);
  add(cWv, 512, 512, 512, o_cWv, 1.f); add(cWo, 512, 512, 512, o_cWo, 1.f);
  add(Wb, 512, 64, 512, o_Wb, 1.f);
  add(W_pos, 48, 512, 64, o_Wpos, 1.f);
  for (int i = 0; i < 6; ++i) {
    add(sWq  + (size_t)i * 512 * 512,  512, 512,  512, o_sQKV[i], SC);
    add(sWkv + (size_t)i * 512 * 1024, 512, 1024, 512, o_sQKV[i] + 512 * 512, 1.f);
    add(sWo  + (size_t)i * 512 * 512,  512, 512,  512, o_sWo[i], 1.f);
    add(fW1  + (size_t)i * 512 * 2048, 512, 2048, 512, o_fW1[i], 1.f);
    add(fW2  + (size_t)i * 2048 * 512, 2048, 512, 2048, o_fW2[i], 1.f);
  }

  // workspace carve
  char* p = (char*)d_ws;
  auto carve = [&](size_t bytes) {
    char* r = p; p += (bytes + 255) & ~(size_t)255; return r;
  };
  short* wtb   = (short*)carve(W * 2);                     // ~40MB
  short* scr   = (short*)carve((size_t)32768 * 64 * 2);    // 4MB scratch (attno)
  short* knvn  = (short*)carve((size_t)32768 * 1024 * 2);  // 64MB  [k | v]
  short* kc    = (short*)carve((size_t)32768 * 512 * 2);   // 32MB K proj
  short* vTc   = (short*)carve((size_t)32768 * 512 * 2);   // 32MB V^T [b][h][64][4096]
  short* latn0 = (short*)carve(262144);
  short* qc    = (short*)carve(262144);
  float* lat   = (float*)carve(4194304);
  float* pm    = (float*)carve(1048576);
  float* pl    = (float*)carve(1048576);
  // aliases into dead regions:
  short* attno = scr;
  float* po    = (float*)knvn;                         // knvn dead after projections
  short* h     = (short*)((char*)knvn + 36 * 1048576); // 2MB
  short* qkv   = (short*)((char*)knvn + 40 * 1048576); // [2048][1024] q|k = 4MB
  short* ffh   = (short*)((char*)knvn + 48 * 1048576); // 8MB
  short* vTs   = (short*)((char*)knvn + 58 * 1048576); // [8][8][64][256] = 2MB

  wtrans_kernel<<<dim3(1024, 36), 256, 0, stream>>>(T, wtb);
  embed2_kernel<<<256, 512, 0, stream>>>(pos, wtb + o_Wpos, b_pos, W_in, b_in, x,
                                         lnk_g, lnk_b, lnv_g, lnv_b, knvn);
  ln_kernel<<<64, 256, 0, stream>>>(latents, lnq_g, lnq_b, latn0, 256);
  gemm64_kernel<0><<<dim3(8, 4), 256, 0, stream>>>(latn0, wtb + o_cWq, nullptr, qc, 256, 512, 512, 512, 512, nullptr);
  gemm_kernel<0><<<dim3(4, 256), 256, 0, stream>>>(knvn, wtb + o_cWk, nullptr, kc, 32768, 512, 512, 1024, 512, nullptr, 0, 0);
  gemm_kernel<0><<<dim3(4, 256), 256, 0, stream>>>(knvn + 512, wtb + o_cWv, nullptr, nullptr, 32768, 512, 512, 1024, 512, vTc, 0, 4096);
  // cross attention: 8 KV segments of 512 tokens; qc shared across b (qbrows=0)
  flashsp_kernel<false><<<dim3(4, 8, 64), 256, 0, stream>>>(qc, kc, vTc, po, pm, pl,
                                                            nullptr, 512, 0,
                                                            (long)4096 * 512, 512, 4096, 512, 3);
  fcomb_kernel<8><<<4096, 256, 0, stream>>>(po, pm, pl, attno);
  // lat = bcast(latents) + attno @ cWo + c_bo   (EPI=4 folds the broadcast)
  gemm64_kernel<4><<<dim3(8, 32), 256, 0, stream>>>(attno, wtb + o_cWo, c_bo, lat, 2048, 512, 512, 512, 512, latents);

  for (int i = 0; i < 6; ++i) {
    ln_kernel<<<512, 256, 0, stream>>>(lat, ln1_g + i * 512, ln1_b + i * 512, h, 2048);
    // q|k -> qkv [2048][1024]; v -> vTs (transposed epilogue, bcol>=1024)
    gemm_kernel<0><<<dim3(12, 16), 256, 0, stream>>>(h, wtb + o_sQKV[i], nullptr, qkv, 2048, 1536, 512, 512, 1024, vTs, 1024, 256);
    // self attention: no split, direct normalized bf16 output (per-batch q)
    flashsp_kernel<true><<<dim3(4, 8, 8), 256, 0, stream>>>(qkv, qkv + 512, vTs,
                                                            nullptr, nullptr, nullptr, attno,
                                                            1024, 256, (long)256 * 1024, 1024, 256, 256, 0);
    gemm64_kernel<2><<<dim3(8, 32), 256, 0, stream>>>(attno, wtb + o_sWo[i], s_bo + i * 512, lat, 2048, 512, 512, 512, 512, nullptr);
    ln_kernel<<<512, 256, 0, stream>>>(lat, ln2_g + i * 512, ln2_b + i * 512, h, 2048);
    gemm_kernel<1><<<dim3(16, 16), 256, 0, stream>>>(h, wtb + o_fW1[i], f_b1 + i * 2048, ffh, 2048, 2048, 512, 512, 2048, nullptr, 0, 0);
    gemm64_kernel<2><<<dim3(8, 32), 256, 0, stream>>>(ffh, wtb + o_fW2[i], f_b2 + i * 512, lat, 2048, 512, 2048, 2048, 512, nullptr);
  }
  ln_kernel<<<512, 256, 0, stream>>>(lat, lnf_g, lnf_b, h, 2048);
  gemm64_kernel<3><<<dim3(1, 32), 256, 0, stream>>>(h, wtb + o_Wb, bbv, outp, 2048, 64, 512, 512, 64, nullptr);
}